// Round 5
// baseline (208.438 us; speedup 1.0000x reference)
//
#include <hip/hip_runtime.h>
#include <hip/hip_bf16.h>
#include <cstdint>
#include <cstddef>

#define SEQ 2048
#define NBATCH 4
#define EMB 1024
#define NH 16
#define HD 64
#define MTOT (NBATCH * SEQ)   // 8192

typedef __attribute__((ext_vector_type(8))) short bf16x8;
typedef __attribute__((ext_vector_type(4))) float f32x4;
typedef __attribute__((ext_vector_type(16))) float f32x16;
typedef unsigned short u16;
typedef unsigned int u32;

__device__ __forceinline__ float bf2f(u16 v) {
  union { u32 u; float f; } c; c.u = ((u32)v) << 16; return c.f;
}
__device__ __forceinline__ u16 f2bf(float f) {
  union { float f; u32 u; } c; c.f = f;
  u32 u = c.u;
  return (u16)((u + 0x7FFFu + ((u >> 16) & 1u)) >> 16);
}

// ---------------- cast fp32 -> bf16 (vectorized) ----------------
__global__ void cast_kernel(const float* __restrict__ in, u16* __restrict__ out, int n4) {
  int stride = gridDim.x * blockDim.x;
  for (int i = blockIdx.x * blockDim.x + threadIdx.x; i < n4; i += stride) {
    float4 v = reinterpret_cast<const float4*>(in)[i];
    ushort4 o;
    o.x = f2bf(v.x); o.y = f2bf(v.y); o.z = f2bf(v.z); o.w = f2bf(v.w);
    reinterpret_cast<ushort4*>(out)[i] = o;
  }
}

// ---------------- RoPE cos/sin table [2][SEQ][32] fp32 ----------------
__global__ void rope_table_kernel(float* __restrict__ tab) {
  int i = blockIdx.x * blockDim.x + threadIdx.x;
  if (i >= SEQ * 32) return;
  int n = i >> 5, j = i & 31;
  float invf = 1.0f / powf(10000.0f, (float)(2 * j) / 64.0f);
  float ang = (float)n * invf;
  tab[i] = cosf(ang);
  tab[SEQ * 32 + i] = sinf(ang);
}

// ---------------- async global->LDS helper (16B) ----------------
__device__ __forceinline__ void gld_lds16(const u16* g, u16* l) {
  __builtin_amdgcn_global_load_lds((const __attribute__((address_space(1))) void*)g,
                                   (__attribute__((address_space(3))) void*)l, 16, 0, 0);
}

// ---------------- GEMM: C[M,N] = A[M,K] * Bw[N,K]^T + bias ----------------
template<bool OUT_F32>
__global__ __launch_bounds__(256, 2)
void gemm_bt(const u16* __restrict__ A, const u16* __restrict__ Bw,
             const float* __restrict__ bias, void* __restrict__ Cout,
             int N, int tiles_n) {
  __shared__ u16 lA[128 * 64];
  __shared__ u16 lB[128 * 64];
  const int K = 1024;
  int bm = blockIdx.x / tiles_n;
  int bn = blockIdx.x % tiles_n;
  int t = threadIdx.x;
  int wave = t >> 6, lane = t & 63;
  int wm = wave >> 1, wn = wave & 1;
  int l15 = lane & 15, l4 = lane >> 4;

  f32x4 acc[4][4];
#pragma unroll
  for (int i = 0; i < 4; ++i)
#pragma unroll
    for (int j = 0; j < 4; ++j) acc[i][j] = (f32x4){0.f, 0.f, 0.f, 0.f};

  int su[4], sr[4], sc[4];
#pragma unroll
  for (int i = 0; i < 4; ++i) {
    int u = (i * 4 + wave) * 64 + lane;
    su[i] = u;
    sr[i] = u >> 3;
    sc[i] = (u & 7) ^ (sr[i] & 7);
  }

  for (int kt = 0; kt < K / 64; ++kt) {
    if (kt) __syncthreads();
#pragma unroll
    for (int i = 0; i < 4; ++i) {
      gld_lds16(A + (size_t)(bm * 128 + sr[i]) * K + kt * 64 + sc[i] * 8, &lA[su[i] * 8]);
      gld_lds16(Bw + (size_t)(bn * 128 + sr[i]) * K + kt * 64 + sc[i] * 8, &lB[su[i] * 8]);
    }
    __syncthreads();
#pragma unroll
    for (int ks = 0; ks < 2; ++ks) {
      bf16x8 af[4], bfr[4];
#pragma unroll
      for (int mb = 0; mb < 4; ++mb) {
        int r = wm * 64 + mb * 16 + l15;
        int cc = (ks * 4 + l4) ^ (r & 7);
        af[mb] = *reinterpret_cast<const bf16x8*>(&lA[r * 64 + cc * 8]);
      }
#pragma unroll
      for (int nb = 0; nb < 4; ++nb) {
        int r = wn * 64 + nb * 16 + l15;
        int cc = (ks * 4 + l4) ^ (r & 7);
        bfr[nb] = *reinterpret_cast<const bf16x8*>(&lB[r * 64 + cc * 8]);
      }
#pragma unroll
      for (int mb = 0; mb < 4; ++mb)
#pragma unroll
        for (int nb = 0; nb < 4; ++nb)
          acc[mb][nb] = __builtin_amdgcn_mfma_f32_16x16x32_bf16(af[mb], bfr[nb], acc[mb][nb], 0, 0, 0);
    }
  }

#pragma unroll
  for (int mb = 0; mb < 4; ++mb)
#pragma unroll
    for (int nb = 0; nb < 4; ++nb) {
      int row0 = bm * 128 + wm * 64 + mb * 16 + l4 * 4;
      int col = bn * 128 + wn * 64 + nb * 16 + l15;
      float bv = bias[col];
#pragma unroll
      for (int r = 0; r < 4; ++r) {
        float v = acc[mb][nb][r] + bv;
        if (OUT_F32)
          reinterpret_cast<float*>(Cout)[(size_t)(row0 + r) * N + col] = v;
        else
          reinterpret_cast<u16*>(Cout)[(size_t)(row0 + r) * N + col] = f2bf(v);
      }
    }
}

// ---------------- RoPE + scatter: qkv[M,3072] -> Q,K [BH][SEQ][64], Vt [BH][64][SEQ] ----------------
__global__ __launch_bounds__(256)
void rope_scatter(const u16* __restrict__ qkv, const float* __restrict__ tab,
                  u16* __restrict__ Q, u16* __restrict__ Kk, u16* __restrict__ Vt) {
  int blk = blockIdx.x;
  int bh = blk >> 5;
  int nt = blk & 31;
  int b = bh >> 4, h = bh & 15;
  int t = threadIdx.x;
  __shared__ u16 vtile[64][72];
  const float* ct = tab;
  const float* st = tab + SEQ * 32;
#pragma unroll
  for (int p = 0; p < 2; ++p) {
    int u = p * 256 + t;
    int r = u >> 3, g = u & 7;
    int n = nt * 64 + r;
    size_t base = (size_t)(b * SEQ + n) * 3072;
    int d0 = g * 8;
    int f0 = d0 & 31;
    bf16x8 qv = *reinterpret_cast<const bf16x8*>(&qkv[base + h * 64 + d0]);
    bf16x8 qp = *reinterpret_cast<const bf16x8*>(&qkv[base + h * 64 + (d0 ^ 32)]);
    bf16x8 kv = *reinterpret_cast<const bf16x8*>(&qkv[base + 1024 + h * 64 + d0]);
    bf16x8 kp = *reinterpret_cast<const bf16x8*>(&qkv[base + 1024 + h * 64 + (d0 ^ 32)]);
    bf16x8 vv = *reinterpret_cast<const bf16x8*>(&qkv[base + 2048 + h * 64 + d0]);
    float4 c0 = *reinterpret_cast<const float4*>(&ct[n * 32 + f0]);
    float4 c1 = *reinterpret_cast<const float4*>(&ct[n * 32 + f0 + 4]);
    float4 s0 = *reinterpret_cast<const float4*>(&st[n * 32 + f0]);
    float4 s1 = *reinterpret_cast<const float4*>(&st[n * 32 + f0 + 4]);
    float sgn = (d0 < 32) ? -1.0f : 1.0f;
    float cs[8] = {c0.x, c0.y, c0.z, c0.w, c1.x, c1.y, c1.z, c1.w};
    float sn[8] = {s0.x, s0.y, s0.z, s0.w, s1.x, s1.y, s1.z, s1.w};
    bf16x8 qo, ko;
#pragma unroll
    for (int j = 0; j < 8; ++j) {
      float qr = bf2f((u16)qv[j]) * cs[j] + sgn * bf2f((u16)qp[j]) * sn[j];
      float kr = bf2f((u16)kv[j]) * cs[j] + sgn * bf2f((u16)kp[j]) * sn[j];
      qo[j] = (short)f2bf(qr * 0.1803368801111163f);  // (1/8)*log2(e)
      ko[j] = (short)f2bf(kr);
      vtile[d0 + j][r] = (u16)vv[j];
    }
    size_t qbase = ((size_t)bh * SEQ + n) * 64 + d0;
    *reinterpret_cast<bf16x8*>(&Q[qbase]) = qo;
    *reinterpret_cast<bf16x8*>(&Kk[qbase]) = ko;
  }
  __syncthreads();
#pragma unroll
  for (int p = 0; p < 2; ++p) {
    int u = p * 256 + t;
    int d = u >> 3, c = u & 7;
    bf16x8 o = *reinterpret_cast<const bf16x8*>(&vtile[d][c * 8]);
    *reinterpret_cast<bf16x8*>(&Vt[((size_t)bh * 64 + d) * SEQ + nt * 64 + c * 8]) = o;
  }
}

// ---------------- attention v5: v4 structure + round-2 numerics (explicit RNE f2bf on P) ----------------
// 256 threads = 4 waves, each wave owns 32 q-rows. grid = 64 heads * 16 q-tiles = 1024 blocks = 4/CU.
// P packed to bf16 with explicit round-to-nearest-even (v_cvt_pk_bf16_f32 is NOT RNE -> 3x error).
// Denominator = sum of unrounded exps (empirically 4.88e-4 in round 2).
__global__ __launch_bounds__(256, 4)
void attn_kernel(const u16* __restrict__ Q, const u16* __restrict__ Kk,
                 const u16* __restrict__ Vt, u16* __restrict__ Out) {
  int bid = blockIdx.x;
  int swz = (bid & 7) * 128 + (bid >> 3);  // XCD-chunked: each XCD owns 8 heads (4MB = L2)
  int bh = swz >> 4;
  int qt = swz & 15;
  int b = bh >> 4, h = bh & 15;
  int t = threadIdx.x;
  int wave = t >> 6, lane = t & 63;
  int l31 = lane & 31, hi = lane >> 5;

  __shared__ u16 lK[2][64 * 64];
  __shared__ u16 lV[2][64 * 64];

  const u16* Qh = Q + (size_t)bh * SEQ * 64;
  const u16* Kh = Kk + (size_t)bh * SEQ * 64;
  const u16* Vh = Vt + (size_t)bh * 64 * SEQ;
  int q0w = qt * 128 + wave * 32;

  // Q fragments (B-operand): col q = l31, k-dim elems d = dc*16 + hi*8 + j
  bf16x8 qf[4];
#pragma unroll
  for (int dc = 0; dc < 4; ++dc)
    qf[dc] = *reinterpret_cast<const bf16x8*>(
        &Qh[(size_t)(q0w + l31) * 64 + dc * 16 + hi * 8]);

  f32x16 oacc[2];
#pragma unroll
  for (int db = 0; db < 2; ++db)
#pragma unroll
    for (int r = 0; r < 16; ++r) oacc[db][r] = 0.f;
  float dn = 0.f;

  // staging: 64x64 bf16 tiles; thread stages 2 chunks of 16B each for K and V.
  auto stage = [&](int buf, int kt) {
#pragma unroll
    for (int p = 0; p < 2; ++p) {
      int u = p * 256 + t;
      int r = u >> 3;
      int c = (u & 7) ^ (r & 7);  // inverse swizzle on global source (rule #21)
      gld_lds16(Kh + (size_t)(kt * 64 + r) * 64 + c * 8, &lK[buf][u * 8]);
      gld_lds16(Vh + (size_t)r * SEQ + kt * 64 + c * 8, &lV[buf][u * 8]);
    }
  };

  union PF { u32 w[4]; bf16x8 v; };
  int cur = 0;
  stage(0, 0);
  for (int kt = 0; kt < SEQ / 64; ++kt) {
    if (kt + 1 < SEQ / 64) {
      stage(cur ^ 1, kt + 1);
      asm volatile("s_waitcnt vmcnt(4)" ::: "memory");  // current tile's 4 loads done
    } else {
      asm volatile("s_waitcnt vmcnt(0)" ::: "memory");
    }
    __builtin_amdgcn_s_barrier();

    // ---- QK^T swapped: S^T[k][q] ; lane: q = l31, k = cb*32 + (r&3)+8*(r>>2)+4*hi
    f32x16 s[2];
#pragma unroll
    for (int cb = 0; cb < 2; ++cb)
#pragma unroll
      for (int r = 0; r < 16; ++r) s[cb][r] = 0.f;
#pragma unroll
    for (int cb = 0; cb < 2; ++cb) {
      int krow = cb * 32 + l31;
#pragma unroll
      for (int dc = 0; dc < 4; ++dc) {
        int ch = (dc * 2 + hi) ^ (l31 & 7);
        bf16x8 kf = *reinterpret_cast<const bf16x8*>(&lK[cur][krow * 64 + ch * 8]);
        s[cb] = __builtin_amdgcn_mfma_f32_32x32x16_bf16(kf, qf[dc], s[cb], 0, 0, 0);
      }
    }

    // ---- softmax in-register: exp2 (denom from unrounded), explicit-RNE pack to bf16
    PF pa[2][2];  // [cb][c(16-k chunk)]
#pragma unroll
    for (int cb = 0; cb < 2; ++cb) {
#pragma unroll
      for (int r = 0; r < 16; ++r) {
        float e = __builtin_amdgcn_exp2f(s[cb][r]);
        s[cb][r] = e;
        dn += e;
      }
#pragma unroll
      for (int c = 0; c < 2; ++c) {
        u32 r0 = f2bf(s[cb][8 * c + 0]), r1 = f2bf(s[cb][8 * c + 1]);
        u32 r2 = f2bf(s[cb][8 * c + 2]), r3 = f2bf(s[cb][8 * c + 3]);
        u32 r4 = f2bf(s[cb][8 * c + 4]), r5 = f2bf(s[cb][8 * c + 5]);
        u32 r6 = f2bf(s[cb][8 * c + 6]), r7 = f2bf(s[cb][8 * c + 7]);
        u32 a1 = r0 | (r1 << 16), a2 = r2 | (r3 << 16);
        u32 b1 = r4 | (r5 << 16), b2 = r6 | (r7 << 16);
        asm("v_permlane32_swap_b32 %0, %1" : "+v"(a1), "+v"(b1));
        asm("v_permlane32_swap_b32 %0, %1" : "+v"(a2), "+v"(b2));
        pa[cb][c].w[0] = a1; pa[cb][c].w[1] = a2;
        pa[cb][c].w[2] = b1; pa[cb][c].w[3] = b2;
      }
    }

    // ---- PV: O[q][d] ; A = P (regs), B = V from LDS (col d = l31)
#pragma unroll
    for (int cb = 0; cb < 2; ++cb)
#pragma unroll
      for (int c = 0; c < 2; ++c)
#pragma unroll
        for (int db = 0; db < 2; ++db) {
          int vrow = db * 32 + l31;
          int ch = (cb * 4 + c * 2 + hi) ^ (l31 & 7);
          bf16x8 vf = *reinterpret_cast<const bf16x8*>(&lV[cur][vrow * 64 + ch * 8]);
          oacc[db] = __builtin_amdgcn_mfma_f32_32x32x16_bf16(pa[cb][c].v, vf, oacc[db], 0, 0, 0);
        }
    __builtin_amdgcn_s_barrier();
    cur ^= 1;
  }

  // ---- epilogue: combine denom halves, normalize, store
  dn += __shfl_xor(dn, 32);
#pragma unroll
  for (int r = 0; r < 16; ++r) {
    int qrel = (r & 3) + 8 * (r >> 2) + 4 * hi;
    float dfull = __shfl(dn, qrel);
    float inv = __builtin_amdgcn_rcpf(dfull);
    int q = q0w + qrel;
#pragma unroll
    for (int db = 0; db < 2; ++db) {
      int d = db * 32 + l31;
      Out[(size_t)(b * SEQ + q) * EMB + h * 64 + d] = f2bf(oacc[db][r] * inv);
    }
  }
}

// ---------------- launch ----------------
extern "C" void kernel_launch(void* const* d_in, const int* in_sizes, int n_in,
                              void* d_out, int out_size, void* d_ws, size_t ws_size,
                              hipStream_t stream) {
  const float* x = (const float*)d_in[0];
  const float* bqkv = (const float*)d_in[2];
  const float* bout = (const float*)d_in[4];
  float* out = (float*)d_out;

  char* ws = (char*)d_ws;
  size_t off = 0;
  auto alloc = [&](size_t bytes) {
    void* p = ws + off;
    off += (bytes + 255) & ~(size_t)255;
    return p;
  };
  u16* xb    = (u16*)alloc((size_t)MTOT * EMB * 2);
  u16* wqkvb = (u16*)alloc((size_t)3 * EMB * EMB * 2);
  u16* woutb = (u16*)alloc((size_t)EMB * EMB * 2);
  u16* qkv   = (u16*)alloc((size_t)MTOT * 3 * EMB * 2);
  u16* Qb    = (u16*)alloc((size_t)64 * SEQ * HD * 2);
  u16* Kb    = (u16*)alloc((size_t)64 * SEQ * HD * 2);
  u16* Vtb   = (u16*)alloc((size_t)64 * HD * SEQ * 2);
  u16* aout  = (u16*)alloc((size_t)MTOT * EMB * 2);
  float* tab = (float*)alloc((size_t)2 * SEQ * 32 * 4);
  (void)ws_size; (void)in_sizes; (void)n_in; (void)out_size;

  cast_kernel<<<2048, 256, 0, stream>>>(x, xb, MTOT * EMB / 4);
  cast_kernel<<<1024, 256, 0, stream>>>((const float*)d_in[1], wqkvb, 3 * EMB * EMB / 4);
  cast_kernel<<<512, 256, 0, stream>>>((const float*)d_in[3], woutb, EMB * EMB / 4);
  rope_table_kernel<<<(SEQ * 32 + 255) / 256, 256, 0, stream>>>(tab);

  gemm_bt<false><<<64 * 24, 256, 0, stream>>>(xb, wqkvb, bqkv, qkv, 3 * EMB, 24);
  rope_scatter<<<64 * 32, 256, 0, stream>>>(qkv, tab, Qb, Kb, Vtb);
  attn_kernel<<<64 * 16, 256, 0, stream>>>(Qb, Kb, Vtb, aout);
  gemm_bt<true><<<64 * 8, 256, 0, stream>>>(aout, woutb, bout, out, EMB, 8);
}

// Round 6
// 203.009 us; speedup vs baseline: 1.0267x; 1.0267x over previous
//
#include <hip/hip_runtime.h>
#include <hip/hip_bf16.h>
#include <cstdint>
#include <cstddef>

#define SEQ 2048
#define NBATCH 4
#define EMB 1024
#define NH 16
#define HD 64
#define MTOT (NBATCH * SEQ)   // 8192

typedef __attribute__((ext_vector_type(8))) short bf16x8;
typedef __attribute__((ext_vector_type(4))) float f32x4;
typedef __attribute__((ext_vector_type(16))) float f32x16;
typedef unsigned short u16;
typedef unsigned int u32;

__device__ __forceinline__ float bf2f(u16 v) {
  union { u32 u; float f; } c; c.u = ((u32)v) << 16; return c.f;
}
__device__ __forceinline__ u16 f2bf(float f) {
  union { float f; u32 u; } c; c.f = f;
  u32 u = c.u;
  return (u16)((u + 0x7FFFu + ((u >> 16) & 1u)) >> 16);
}
__device__ __forceinline__ u32 f2u(float f) {
  union { float f; u32 u; } c; c.f = f; return c.u;
}

// ---------------- cast fp32 -> bf16 (vectorized) ----------------
__global__ void cast_kernel(const float* __restrict__ in, u16* __restrict__ out, int n4) {
  int stride = gridDim.x * blockDim.x;
  for (int i = blockIdx.x * blockDim.x + threadIdx.x; i < n4; i += stride) {
    float4 v = reinterpret_cast<const float4*>(in)[i];
    ushort4 o;
    o.x = f2bf(v.x); o.y = f2bf(v.y); o.z = f2bf(v.z); o.w = f2bf(v.w);
    reinterpret_cast<ushort4*>(out)[i] = o;
  }
}

// ---------------- RoPE cos/sin table [2][SEQ][32] fp32 ----------------
__global__ void rope_table_kernel(float* __restrict__ tab) {
  int i = blockIdx.x * blockDim.x + threadIdx.x;
  if (i >= SEQ * 32) return;
  int n = i >> 5, j = i & 31;
  float invf = 1.0f / powf(10000.0f, (float)(2 * j) / 64.0f);
  float ang = (float)n * invf;
  tab[i] = cosf(ang);
  tab[SEQ * 32 + i] = sinf(ang);
}

// ---------------- async global->LDS helper (16B) ----------------
__device__ __forceinline__ void gld_lds16(const u16* g, u16* l) {
  __builtin_amdgcn_global_load_lds((const __attribute__((address_space(1))) void*)g,
                                   (__attribute__((address_space(3))) void*)l, 16, 0, 0);
}

// ---------------- GEMM: C[M,N] = A[M,K] * Bw[N,K]^T + bias ----------------
template<bool OUT_F32>
__global__ __launch_bounds__(256, 2)
void gemm_bt(const u16* __restrict__ A, const u16* __restrict__ Bw,
             const float* __restrict__ bias, void* __restrict__ Cout,
             int N, int tiles_n) {
  __shared__ u16 lA[128 * 64];
  __shared__ u16 lB[128 * 64];
  const int K = 1024;
  int bm = blockIdx.x / tiles_n;
  int bn = blockIdx.x % tiles_n;
  int t = threadIdx.x;
  int wave = t >> 6, lane = t & 63;
  int wm = wave >> 1, wn = wave & 1;
  int l15 = lane & 15, l4 = lane >> 4;

  f32x4 acc[4][4];
#pragma unroll
  for (int i = 0; i < 4; ++i)
#pragma unroll
    for (int j = 0; j < 4; ++j) acc[i][j] = (f32x4){0.f, 0.f, 0.f, 0.f};

  int su[4], sr[4], sc[4];
#pragma unroll
  for (int i = 0; i < 4; ++i) {
    int u = (i * 4 + wave) * 64 + lane;
    su[i] = u;
    sr[i] = u >> 3;
    sc[i] = (u & 7) ^ (sr[i] & 7);
  }

  for (int kt = 0; kt < K / 64; ++kt) {
    if (kt) __syncthreads();
#pragma unroll
    for (int i = 0; i < 4; ++i) {
      gld_lds16(A + (size_t)(bm * 128 + sr[i]) * K + kt * 64 + sc[i] * 8, &lA[su[i] * 8]);
      gld_lds16(Bw + (size_t)(bn * 128 + sr[i]) * K + kt * 64 + sc[i] * 8, &lB[su[i] * 8]);
    }
    __syncthreads();
#pragma unroll
    for (int ks = 0; ks < 2; ++ks) {
      bf16x8 af[4], bfr[4];
#pragma unroll
      for (int mb = 0; mb < 4; ++mb) {
        int r = wm * 64 + mb * 16 + l15;
        int cc = (ks * 4 + l4) ^ (r & 7);
        af[mb] = *reinterpret_cast<const bf16x8*>(&lA[r * 64 + cc * 8]);
      }
#pragma unroll
      for (int nb = 0; nb < 4; ++nb) {
        int r = wn * 64 + nb * 16 + l15;
        int cc = (ks * 4 + l4) ^ (r & 7);
        bfr[nb] = *reinterpret_cast<const bf16x8*>(&lB[r * 64 + cc * 8]);
      }
#pragma unroll
      for (int mb = 0; mb < 4; ++mb)
#pragma unroll
        for (int nb = 0; nb < 4; ++nb)
          acc[mb][nb] = __builtin_amdgcn_mfma_f32_16x16x32_bf16(af[mb], bfr[nb], acc[mb][nb], 0, 0, 0);
    }
  }

#pragma unroll
  for (int mb = 0; mb < 4; ++mb)
#pragma unroll
    for (int nb = 0; nb < 4; ++nb) {
      int row0 = bm * 128 + wm * 64 + mb * 16 + l4 * 4;
      int col = bn * 128 + wn * 64 + nb * 16 + l15;
      float bv = bias[col];
#pragma unroll
      for (int r = 0; r < 4; ++r) {
        float v = acc[mb][nb][r] + bv;
        if (OUT_F32)
          reinterpret_cast<float*>(Cout)[(size_t)(row0 + r) * N + col] = v;
        else
          reinterpret_cast<u16*>(Cout)[(size_t)(row0 + r) * N + col] = f2bf(v);
      }
    }
}

// ---------------- RoPE + scatter: qkv[M,3072] -> Q,K [BH][SEQ][64], Vt [BH][64][SEQ] ----------------
__global__ __launch_bounds__(256)
void rope_scatter(const u16* __restrict__ qkv, const float* __restrict__ tab,
                  u16* __restrict__ Q, u16* __restrict__ Kk, u16* __restrict__ Vt) {
  int blk = blockIdx.x;
  int bh = blk >> 5;
  int nt = blk & 31;
  int b = bh >> 4, h = bh & 15;
  int t = threadIdx.x;
  __shared__ u16 vtile[64][72];
  const float* ct = tab;
  const float* st = tab + SEQ * 32;
#pragma unroll
  for (int p = 0; p < 2; ++p) {
    int u = p * 256 + t;
    int r = u >> 3, g = u & 7;
    int n = nt * 64 + r;
    size_t base = (size_t)(b * SEQ + n) * 3072;
    int d0 = g * 8;
    int f0 = d0 & 31;
    bf16x8 qv = *reinterpret_cast<const bf16x8*>(&qkv[base + h * 64 + d0]);
    bf16x8 qp = *reinterpret_cast<const bf16x8*>(&qkv[base + h * 64 + (d0 ^ 32)]);
    bf16x8 kv = *reinterpret_cast<const bf16x8*>(&qkv[base + 1024 + h * 64 + d0]);
    bf16x8 kp = *reinterpret_cast<const bf16x8*>(&qkv[base + 1024 + h * 64 + (d0 ^ 32)]);
    bf16x8 vv = *reinterpret_cast<const bf16x8*>(&qkv[base + 2048 + h * 64 + d0]);
    float4 c0 = *reinterpret_cast<const float4*>(&ct[n * 32 + f0]);
    float4 c1 = *reinterpret_cast<const float4*>(&ct[n * 32 + f0 + 4]);
    float4 s0 = *reinterpret_cast<const float4*>(&st[n * 32 + f0]);
    float4 s1 = *reinterpret_cast<const float4*>(&st[n * 32 + f0 + 4]);
    float sgn = (d0 < 32) ? -1.0f : 1.0f;
    float cs[8] = {c0.x, c0.y, c0.z, c0.w, c1.x, c1.y, c1.z, c1.w};
    float sn[8] = {s0.x, s0.y, s0.z, s0.w, s1.x, s1.y, s1.z, s1.w};
    bf16x8 qo, ko;
#pragma unroll
    for (int j = 0; j < 8; ++j) {
      float qr = bf2f((u16)qv[j]) * cs[j] + sgn * bf2f((u16)qp[j]) * sn[j];
      float kr = bf2f((u16)kv[j]) * cs[j] + sgn * bf2f((u16)kp[j]) * sn[j];
      qo[j] = (short)f2bf(qr * 0.1803368801111163f);  // (1/8)*log2(e)
      ko[j] = (short)f2bf(kr);
      vtile[d0 + j][r] = (u16)vv[j];
    }
    size_t qbase = ((size_t)bh * SEQ + n) * 64 + d0;
    *reinterpret_cast<bf16x8*>(&Q[qbase]) = qo;
    *reinterpret_cast<bf16x8*>(&Kk[qbase]) = ko;
  }
  __syncthreads();
#pragma unroll
  for (int p = 0; p < 2; ++p) {
    int u = p * 256 + t;
    int d = u >> 3, c = u & 7;
    bf16x8 o = *reinterpret_cast<const bf16x8*>(&vtile[d][c * 8]);
    *reinterpret_cast<bf16x8*>(&Vt[((size_t)bh * 64 + d) * SEQ + nt * 64 + c * 8]) = o;
  }
}

// ---------------- attention v6: 2-wave blocks, 64 q-rows/wave, RHU+perm softmax pack ----------------
// 128 threads = 2 waves; block q-tile = 128 rows; grid = 64 heads * 16 tiles = 1024 blocks = 4/CU.
// LDS 32KB dbuf (128KB/CU). P packed to bf16 via round-half-up (u+0x8000) + v_perm_b32 byte-select
// (unbiased, ~1.75 VALU/elem vs ~4 for explicit RNE); denom from unrounded exps (round-2 numerics).
__global__ __launch_bounds__(128, 2)
void attn_kernel(const u16* __restrict__ Q, const u16* __restrict__ Kk,
                 const u16* __restrict__ Vt, u16* __restrict__ Out) {
  int bid = blockIdx.x;
  int swz = (bid & 7) * 128 + (bid >> 3);  // XCD-chunked: each XCD owns 8 heads (4MB = L2)
  int bh = swz >> 4;
  int qt = swz & 15;
  int b = bh >> 4, h = bh & 15;
  int t = threadIdx.x;
  int wave = t >> 6, lane = t & 63;
  int l31 = lane & 31, hi = lane >> 5;

  __shared__ u16 lK[2][64 * 64];
  __shared__ u16 lV[2][64 * 64];

  const u16* Qh = Q + (size_t)bh * SEQ * 64;
  const u16* Kh = Kk + (size_t)bh * SEQ * 64;
  const u16* Vh = Vt + (size_t)bh * 64 * SEQ;
  int q0w = qt * 128 + wave * 64;

  // Q fragments (B-operand): col q = l31, k-dim elems d = dc*16 + hi*8 + j
  bf16x8 qf[2][4];
#pragma unroll
  for (int qb = 0; qb < 2; ++qb)
#pragma unroll
    for (int dc = 0; dc < 4; ++dc)
      qf[qb][dc] = *reinterpret_cast<const bf16x8*>(
          &Qh[(size_t)(q0w + qb * 32 + l31) * 64 + dc * 16 + hi * 8]);

  f32x16 oacc[2][2];
#pragma unroll
  for (int qb = 0; qb < 2; ++qb)
#pragma unroll
    for (int db = 0; db < 2; ++db)
#pragma unroll
      for (int r = 0; r < 16; ++r) oacc[qb][db][r] = 0.f;
  float dn[2] = {0.f, 0.f};

  // staging: 64x64 bf16 tiles; 128 threads stage 4 chunks of 16B each for K and V.
  auto stage = [&](int buf, int kt) {
#pragma unroll
    for (int p = 0; p < 4; ++p) {
      int u = p * 128 + t;
      int r = u >> 3;
      int c = (u & 7) ^ (r & 7);  // inverse swizzle on global source (rule #21)
      gld_lds16(Kh + (size_t)(kt * 64 + r) * 64 + c * 8, &lK[buf][u * 8]);
      gld_lds16(Vh + (size_t)r * SEQ + kt * 64 + c * 8, &lV[buf][u * 8]);
    }
  };

  union PF { u32 w[4]; bf16x8 v; };
  int cur = 0;
  stage(0, 0);
  for (int kt = 0; kt < SEQ / 64; ++kt) {
    if (kt + 1 < SEQ / 64) {
      stage(cur ^ 1, kt + 1);
      asm volatile("s_waitcnt vmcnt(8)" ::: "memory");  // current tile's 8 loads done; next's in flight
    } else {
      asm volatile("s_waitcnt vmcnt(0)" ::: "memory");
    }
    __builtin_amdgcn_s_barrier();

    // ---- QK^T swapped: S^T[k][q] ; lane: q = l31, k = cb*32 + (r&3)+8*(r>>2)+4*hi
    f32x16 s[2][2];
#pragma unroll
    for (int qb = 0; qb < 2; ++qb)
#pragma unroll
      for (int cb = 0; cb < 2; ++cb)
#pragma unroll
        for (int r = 0; r < 16; ++r) s[qb][cb][r] = 0.f;
#pragma unroll
    for (int cb = 0; cb < 2; ++cb) {
      int krow = cb * 32 + l31;
#pragma unroll
      for (int dc = 0; dc < 4; ++dc) {
        int ch = (dc * 2 + hi) ^ (l31 & 7);
        bf16x8 kf = *reinterpret_cast<const bf16x8*>(&lK[cur][krow * 64 + ch * 8]);
        s[0][cb] = __builtin_amdgcn_mfma_f32_32x32x16_bf16(kf, qf[0][dc], s[0][cb], 0, 0, 0);
        s[1][cb] = __builtin_amdgcn_mfma_f32_32x32x16_bf16(kf, qf[1][dc], s[1][cb], 0, 0, 0);
      }
    }

    // ---- softmax in-register: exp2 (denom unrounded), round-half-up + v_perm pack to bf16
    PF pa[2][2][2];  // [qb][cb][c(16-k chunk)]
#pragma unroll
    for (int qb = 0; qb < 2; ++qb)
#pragma unroll
      for (int cb = 0; cb < 2; ++cb) {
#pragma unroll
        for (int r = 0; r < 16; ++r) {
          float e = __builtin_amdgcn_exp2f(s[qb][cb][r]);
          s[qb][cb][r] = e;
          dn[qb] += e;
        }
#pragma unroll
        for (int c = 0; c < 2; ++c) {
          u32 u0 = f2u(s[qb][cb][8 * c + 0]) + 0x8000u;
          u32 u1 = f2u(s[qb][cb][8 * c + 1]) + 0x8000u;
          u32 u2 = f2u(s[qb][cb][8 * c + 2]) + 0x8000u;
          u32 u3 = f2u(s[qb][cb][8 * c + 3]) + 0x8000u;
          u32 u4 = f2u(s[qb][cb][8 * c + 4]) + 0x8000u;
          u32 u5 = f2u(s[qb][cb][8 * c + 5]) + 0x8000u;
          u32 u6 = f2u(s[qb][cb][8 * c + 6]) + 0x8000u;
          u32 u7 = f2u(s[qb][cb][8 * c + 7]) + 0x8000u;
          u32 a1 = __builtin_amdgcn_perm(u1, u0, 0x07060302);  // bf16(e1)<<16 | bf16(e0)
          u32 a2 = __builtin_amdgcn_perm(u3, u2, 0x07060302);
          u32 b1 = __builtin_amdgcn_perm(u5, u4, 0x07060302);
          u32 b2 = __builtin_amdgcn_perm(u7, u6, 0x07060302);
          asm("v_permlane32_swap_b32 %0, %1" : "+v"(a1), "+v"(b1));
          asm("v_permlane32_swap_b32 %0, %1" : "+v"(a2), "+v"(b2));
          pa[qb][cb][c].w[0] = a1; pa[qb][cb][c].w[1] = a2;
          pa[qb][cb][c].w[2] = b1; pa[qb][cb][c].w[3] = b2;
        }
      }

    // ---- PV: O[q][d] ; A = P (regs), B = V from LDS (col d = l31); V frags shared across qb
#pragma unroll
    for (int cb = 0; cb < 2; ++cb)
#pragma unroll
      for (int c = 0; c < 2; ++c)
#pragma unroll
        for (int db = 0; db < 2; ++db) {
          int vrow = db * 32 + l31;
          int ch = (cb * 4 + c * 2 + hi) ^ (l31 & 7);
          bf16x8 vf = *reinterpret_cast<const bf16x8*>(&lV[cur][vrow * 64 + ch * 8]);
          oacc[0][db] = __builtin_amdgcn_mfma_f32_32x32x16_bf16(pa[0][cb][c].v, vf, oacc[0][db], 0, 0, 0);
          oacc[1][db] = __builtin_amdgcn_mfma_f32_32x32x16_bf16(pa[1][cb][c].v, vf, oacc[1][db], 0, 0, 0);
        }
    __builtin_amdgcn_s_barrier();
    cur ^= 1;
  }

  // ---- epilogue: combine denom halves, normalize, store
#pragma unroll
  for (int qb = 0; qb < 2; ++qb) dn[qb] += __shfl_xor(dn[qb], 32);
#pragma unroll
  for (int qb = 0; qb < 2; ++qb)
#pragma unroll
    for (int r = 0; r < 16; ++r) {
      int qrel = (r & 3) + 8 * (r >> 2) + 4 * hi;
      float dfull = __shfl(dn[qb], qrel);
      float inv = __builtin_amdgcn_rcpf(dfull);
      int q = q0w + qb * 32 + qrel;
#pragma unroll
      for (int db = 0; db < 2; ++db) {
        int d = db * 32 + l31;
        Out[(size_t)(b * SEQ + q) * EMB + h * 64 + d] = f2bf(oacc[qb][db][r] * inv);
      }
    }
}

// ---------------- launch ----------------
extern "C" void kernel_launch(void* const* d_in, const int* in_sizes, int n_in,
                              void* d_out, int out_size, void* d_ws, size_t ws_size,
                              hipStream_t stream) {
  const float* x = (const float*)d_in[0];
  const float* bqkv = (const float*)d_in[2];
  const float* bout = (const float*)d_in[4];
  float* out = (float*)d_out;

  char* ws = (char*)d_ws;
  size_t off = 0;
  auto alloc = [&](size_t bytes) {
    void* p = ws + off;
    off += (bytes + 255) & ~(size_t)255;
    return p;
  };
  u16* xb    = (u16*)alloc((size_t)MTOT * EMB * 2);
  u16* wqkvb = (u16*)alloc((size_t)3 * EMB * EMB * 2);
  u16* woutb = (u16*)alloc((size_t)EMB * EMB * 2);
  u16* qkv   = (u16*)alloc((size_t)MTOT * 3 * EMB * 2);
  u16* Qb    = (u16*)alloc((size_t)64 * SEQ * HD * 2);
  u16* Kb    = (u16*)alloc((size_t)64 * SEQ * HD * 2);
  u16* Vtb   = (u16*)alloc((size_t)64 * HD * SEQ * 2);
  u16* aout  = (u16*)alloc((size_t)MTOT * EMB * 2);
  float* tab = (float*)alloc((size_t)2 * SEQ * 32 * 4);
  (void)ws_size; (void)in_sizes; (void)n_in; (void)out_size;

  cast_kernel<<<2048, 256, 0, stream>>>(x, xb, MTOT * EMB / 4);
  cast_kernel<<<1024, 256, 0, stream>>>((const float*)d_in[1], wqkvb, 3 * EMB * EMB / 4);
  cast_kernel<<<512, 256, 0, stream>>>((const float*)d_in[3], woutb, EMB * EMB / 4);
  rope_table_kernel<<<(SEQ * 32 + 255) / 256, 256, 0, stream>>>(tab);

  gemm_bt<false><<<64 * 24, 256, 0, stream>>>(xb, wqkvb, bqkv, qkv, 3 * EMB, 24);
  rope_scatter<<<64 * 32, 256, 0, stream>>>(qkv, tab, Qb, Kb, Vtb);
  attn_kernel<<<64 * 16, 128, 0, stream>>>(Qb, Kb, Vtb, aout);
  gemm_bt<true><<<64 * 8, 256, 0, stream>>>(aout, woutb, bout, out, EMB, 8);
}

// Round 7
// 199.459 us; speedup vs baseline: 1.0450x; 1.0178x over previous
//
#include <hip/hip_runtime.h>
#include <hip/hip_bf16.h>
#include <cstdint>
#include <cstddef>

#define SEQ 2048
#define NBATCH 4
#define EMB 1024
#define NH 16
#define HD 64
#define MTOT (NBATCH * SEQ)   // 8192

typedef __attribute__((ext_vector_type(8))) short bf16x8;
typedef __attribute__((ext_vector_type(4))) float f32x4;
typedef __attribute__((ext_vector_type(16))) float f32x16;
typedef unsigned short u16;
typedef unsigned int u32;

__device__ __forceinline__ float bf2f(u16 v) {
  union { u32 u; float f; } c; c.u = ((u32)v) << 16; return c.f;
}
__device__ __forceinline__ u16 f2bf(float f) {
  union { float f; u32 u; } c; c.f = f;
  u32 u = c.u;
  return (u16)((u + 0x7FFFu + ((u >> 16) & 1u)) >> 16);
}
__device__ __forceinline__ u32 f2u(float f) {
  union { float f; u32 u; } c; c.f = f; return c.u;
}

// ---------------- cast fp32 -> bf16 (vectorized) ----------------
__global__ void cast_kernel(const float* __restrict__ in, u16* __restrict__ out, int n4) {
  int stride = gridDim.x * blockDim.x;
  for (int i = blockIdx.x * blockDim.x + threadIdx.x; i < n4; i += stride) {
    float4 v = reinterpret_cast<const float4*>(in)[i];
    ushort4 o;
    o.x = f2bf(v.x); o.y = f2bf(v.y); o.z = f2bf(v.z); o.w = f2bf(v.w);
    reinterpret_cast<ushort4*>(out)[i] = o;
  }
}

// ---------------- RoPE cos/sin table [2][SEQ][32] fp32 ----------------
__global__ void rope_table_kernel(float* __restrict__ tab) {
  int i = blockIdx.x * blockDim.x + threadIdx.x;
  if (i >= SEQ * 32) return;
  int n = i >> 5, j = i & 31;
  float invf = 1.0f / powf(10000.0f, (float)(2 * j) / 64.0f);
  float ang = (float)n * invf;
  tab[i] = cosf(ang);
  tab[SEQ * 32 + i] = sinf(ang);
}

// ---------------- async global->LDS helper (16B) ----------------
__device__ __forceinline__ void gld_lds16(const u16* g, u16* l) {
  __builtin_amdgcn_global_load_lds((const __attribute__((address_space(1))) void*)g,
                                   (__attribute__((address_space(3))) void*)l, 16, 0, 0);
}

// ---------------- GEMM: C[M,N] = A[M,K] * Bw[N,K]^T + bias ----------------
template<bool OUT_F32>
__global__ __launch_bounds__(256, 2)
void gemm_bt(const u16* __restrict__ A, const u16* __restrict__ Bw,
             const float* __restrict__ bias, void* __restrict__ Cout,
             int N, int tiles_n) {
  __shared__ u16 lA[128 * 64];
  __shared__ u16 lB[128 * 64];
  const int K = 1024;
  int bm = blockIdx.x / tiles_n;
  int bn = blockIdx.x % tiles_n;
  int t = threadIdx.x;
  int wave = t >> 6, lane = t & 63;
  int wm = wave >> 1, wn = wave & 1;
  int l15 = lane & 15, l4 = lane >> 4;

  f32x4 acc[4][4];
#pragma unroll
  for (int i = 0; i < 4; ++i)
#pragma unroll
    for (int j = 0; j < 4; ++j) acc[i][j] = (f32x4){0.f, 0.f, 0.f, 0.f};

  int su[4], sr[4], sc[4];
#pragma unroll
  for (int i = 0; i < 4; ++i) {
    int u = (i * 4 + wave) * 64 + lane;
    su[i] = u;
    sr[i] = u >> 3;
    sc[i] = (u & 7) ^ (sr[i] & 7);
  }

  for (int kt = 0; kt < K / 64; ++kt) {
    if (kt) __syncthreads();
#pragma unroll
    for (int i = 0; i < 4; ++i) {
      gld_lds16(A + (size_t)(bm * 128 + sr[i]) * K + kt * 64 + sc[i] * 8, &lA[su[i] * 8]);
      gld_lds16(Bw + (size_t)(bn * 128 + sr[i]) * K + kt * 64 + sc[i] * 8, &lB[su[i] * 8]);
    }
    __syncthreads();
#pragma unroll
    for (int ks = 0; ks < 2; ++ks) {
      bf16x8 af[4], bfr[4];
#pragma unroll
      for (int mb = 0; mb < 4; ++mb) {
        int r = wm * 64 + mb * 16 + l15;
        int cc = (ks * 4 + l4) ^ (r & 7);
        af[mb] = *reinterpret_cast<const bf16x8*>(&lA[r * 64 + cc * 8]);
      }
#pragma unroll
      for (int nb = 0; nb < 4; ++nb) {
        int r = wn * 64 + nb * 16 + l15;
        int cc = (ks * 4 + l4) ^ (r & 7);
        bfr[nb] = *reinterpret_cast<const bf16x8*>(&lB[r * 64 + cc * 8]);
      }
#pragma unroll
      for (int mb = 0; mb < 4; ++mb)
#pragma unroll
        for (int nb = 0; nb < 4; ++nb)
          acc[mb][nb] = __builtin_amdgcn_mfma_f32_16x16x32_bf16(af[mb], bfr[nb], acc[mb][nb], 0, 0, 0);
    }
  }

#pragma unroll
  for (int mb = 0; mb < 4; ++mb)
#pragma unroll
    for (int nb = 0; nb < 4; ++nb) {
      int row0 = bm * 128 + wm * 64 + mb * 16 + l4 * 4;
      int col = bn * 128 + wn * 64 + nb * 16 + l15;
      float bv = bias[col];
#pragma unroll
      for (int r = 0; r < 4; ++r) {
        float v = acc[mb][nb][r] + bv;
        if (OUT_F32)
          reinterpret_cast<float*>(Cout)[(size_t)(row0 + r) * N + col] = v;
        else
          reinterpret_cast<u16*>(Cout)[(size_t)(row0 + r) * N + col] = f2bf(v);
      }
    }
}

// ---------------- RoPE + scatter: qkv[M,3072] -> Q,K [BH][SEQ][64], Vt [BH][64][SEQ] ----------------
__global__ __launch_bounds__(256)
void rope_scatter(const u16* __restrict__ qkv, const float* __restrict__ tab,
                  u16* __restrict__ Q, u16* __restrict__ Kk, u16* __restrict__ Vt) {
  int blk = blockIdx.x;
  int bh = blk >> 5;
  int nt = blk & 31;
  int b = bh >> 4, h = bh & 15;
  int t = threadIdx.x;
  __shared__ u16 vtile[64][72];
  const float* ct = tab;
  const float* st = tab + SEQ * 32;
#pragma unroll
  for (int p = 0; p < 2; ++p) {
    int u = p * 256 + t;
    int r = u >> 3, g = u & 7;
    int n = nt * 64 + r;
    size_t base = (size_t)(b * SEQ + n) * 3072;
    int d0 = g * 8;
    int f0 = d0 & 31;
    bf16x8 qv = *reinterpret_cast<const bf16x8*>(&qkv[base + h * 64 + d0]);
    bf16x8 qp = *reinterpret_cast<const bf16x8*>(&qkv[base + h * 64 + (d0 ^ 32)]);
    bf16x8 kv = *reinterpret_cast<const bf16x8*>(&qkv[base + 1024 + h * 64 + d0]);
    bf16x8 kp = *reinterpret_cast<const bf16x8*>(&qkv[base + 1024 + h * 64 + (d0 ^ 32)]);
    bf16x8 vv = *reinterpret_cast<const bf16x8*>(&qkv[base + 2048 + h * 64 + d0]);
    float4 c0 = *reinterpret_cast<const float4*>(&ct[n * 32 + f0]);
    float4 c1 = *reinterpret_cast<const float4*>(&ct[n * 32 + f0 + 4]);
    float4 s0 = *reinterpret_cast<const float4*>(&st[n * 32 + f0]);
    float4 s1 = *reinterpret_cast<const float4*>(&st[n * 32 + f0 + 4]);
    float sgn = (d0 < 32) ? -1.0f : 1.0f;
    float cs[8] = {c0.x, c0.y, c0.z, c0.w, c1.x, c1.y, c1.z, c1.w};
    float sn[8] = {s0.x, s0.y, s0.z, s0.w, s1.x, s1.y, s1.z, s1.w};
    bf16x8 qo, ko;
#pragma unroll
    for (int j = 0; j < 8; ++j) {
      float qr = bf2f((u16)qv[j]) * cs[j] + sgn * bf2f((u16)qp[j]) * sn[j];
      float kr = bf2f((u16)kv[j]) * cs[j] + sgn * bf2f((u16)kp[j]) * sn[j];
      qo[j] = (short)f2bf(qr * 0.1803368801111163f);  // (1/8)*log2(e)
      ko[j] = (short)f2bf(kr);
      vtile[d0 + j][r] = (u16)vv[j];
    }
    size_t qbase = ((size_t)bh * SEQ + n) * 64 + d0;
    *reinterpret_cast<bf16x8*>(&Q[qbase]) = qo;
    *reinterpret_cast<bf16x8*>(&Kk[qbase]) = ko;
  }
  __syncthreads();
#pragma unroll
  for (int p = 0; p < 2; ++p) {
    int u = p * 256 + t;
    int d = u >> 3, c = u & 7;
    bf16x8 o = *reinterpret_cast<const bf16x8*>(&vtile[d][c * 8]);
    *reinterpret_cast<bf16x8*>(&Vt[((size_t)bh * 64 + d) * SEQ + nt * 64 + c * 8]) = o;
  }
}

// ---------------- attention v7: 4-wave blocks, 32 q-rows/wave (16 waves/CU), perm pack ----------------
// 256 threads = 4 waves; block q-tile = 128 rows; grid = 64 heads * 16 tiles = 1024 blocks = 4/CU.
// LDS 32KB dbuf (128KB/CU). Softmax: exp2 (denom unrounded) + round-half-up (u+0x8000) +
// v_perm_b32 byte-pack (unbiased, ~1.75 VALU/elem) + permlane32_swap. s_setprio around MFMA (T5).
__global__ __launch_bounds__(256, 4)
void attn_kernel(const u16* __restrict__ Q, const u16* __restrict__ Kk,
                 const u16* __restrict__ Vt, u16* __restrict__ Out) {
  int bid = blockIdx.x;
  int swz = (bid & 7) * 128 + (bid >> 3);  // XCD-chunked: each XCD owns 8 heads (4MB = L2)
  int bh = swz >> 4;
  int qt = swz & 15;
  int b = bh >> 4, h = bh & 15;
  int t = threadIdx.x;
  int wave = t >> 6, lane = t & 63;
  int l31 = lane & 31, hi = lane >> 5;

  __shared__ u16 lK[2][64 * 64];
  __shared__ u16 lV[2][64 * 64];

  const u16* Qh = Q + (size_t)bh * SEQ * 64;
  const u16* Kh = Kk + (size_t)bh * SEQ * 64;
  const u16* Vh = Vt + (size_t)bh * 64 * SEQ;
  int q0w = qt * 128 + wave * 32;

  // Q fragments (B-operand): col q = l31, k-dim elems d = dc*16 + hi*8 + j
  bf16x8 qf[4];
#pragma unroll
  for (int dc = 0; dc < 4; ++dc)
    qf[dc] = *reinterpret_cast<const bf16x8*>(
        &Qh[(size_t)(q0w + l31) * 64 + dc * 16 + hi * 8]);

  f32x16 oacc[2];
#pragma unroll
  for (int db = 0; db < 2; ++db)
#pragma unroll
    for (int r = 0; r < 16; ++r) oacc[db][r] = 0.f;
  float dn = 0.f;

  // staging: 64x64 bf16 tiles; 256 threads stage 2 chunks of 16B each for K and V.
  auto stage = [&](int buf, int kt) {
#pragma unroll
    for (int p = 0; p < 2; ++p) {
      int u = p * 256 + t;
      int r = u >> 3;
      int c = (u & 7) ^ (r & 7);  // inverse swizzle on global source (rule #21)
      gld_lds16(Kh + (size_t)(kt * 64 + r) * 64 + c * 8, &lK[buf][u * 8]);
      gld_lds16(Vh + (size_t)r * SEQ + kt * 64 + c * 8, &lV[buf][u * 8]);
    }
  };

  union PF { u32 w[4]; bf16x8 v; };
  int cur = 0;
  stage(0, 0);
  for (int kt = 0; kt < SEQ / 64; ++kt) {
    if (kt + 1 < SEQ / 64) {
      stage(cur ^ 1, kt + 1);
      asm volatile("s_waitcnt vmcnt(4)" ::: "memory");  // current tile's 4 loads done; next in flight
    } else {
      asm volatile("s_waitcnt vmcnt(0)" ::: "memory");
    }
    __builtin_amdgcn_s_barrier();

    // ---- QK^T swapped: S^T[k][q] ; lane: q = l31, k = cb*32 + (r&3)+8*(r>>2)+4*hi
    f32x16 s[2];
#pragma unroll
    for (int cb = 0; cb < 2; ++cb)
#pragma unroll
      for (int r = 0; r < 16; ++r) s[cb][r] = 0.f;
    __builtin_amdgcn_s_setprio(1);
#pragma unroll
    for (int cb = 0; cb < 2; ++cb) {
      int krow = cb * 32 + l31;
#pragma unroll
      for (int dc = 0; dc < 4; ++dc) {
        int ch = (dc * 2 + hi) ^ (l31 & 7);
        bf16x8 kf = *reinterpret_cast<const bf16x8*>(&lK[cur][krow * 64 + ch * 8]);
        s[cb] = __builtin_amdgcn_mfma_f32_32x32x16_bf16(kf, qf[dc], s[cb], 0, 0, 0);
      }
    }
    __builtin_amdgcn_s_setprio(0);

    // ---- softmax in-register: exp2 (denom unrounded), round-half-up + v_perm pack to bf16
    PF pa[2][2];  // [cb][c(16-k chunk)]
#pragma unroll
    for (int cb = 0; cb < 2; ++cb) {
#pragma unroll
      for (int r = 0; r < 16; ++r) {
        float e = __builtin_amdgcn_exp2f(s[cb][r]);
        s[cb][r] = e;
        dn += e;
      }
#pragma unroll
      for (int c = 0; c < 2; ++c) {
        u32 u0 = f2u(s[cb][8 * c + 0]) + 0x8000u;
        u32 u1 = f2u(s[cb][8 * c + 1]) + 0x8000u;
        u32 u2 = f2u(s[cb][8 * c + 2]) + 0x8000u;
        u32 u3 = f2u(s[cb][8 * c + 3]) + 0x8000u;
        u32 u4 = f2u(s[cb][8 * c + 4]) + 0x8000u;
        u32 u5 = f2u(s[cb][8 * c + 5]) + 0x8000u;
        u32 u6 = f2u(s[cb][8 * c + 6]) + 0x8000u;
        u32 u7 = f2u(s[cb][8 * c + 7]) + 0x8000u;
        u32 a1 = __builtin_amdgcn_perm(u1, u0, 0x07060302);  // bf16(e1)<<16 | bf16(e0)
        u32 a2 = __builtin_amdgcn_perm(u3, u2, 0x07060302);
        u32 b1 = __builtin_amdgcn_perm(u5, u4, 0x07060302);
        u32 b2 = __builtin_amdgcn_perm(u7, u6, 0x07060302);
        asm("v_permlane32_swap_b32 %0, %1" : "+v"(a1), "+v"(b1));
        asm("v_permlane32_swap_b32 %0, %1" : "+v"(a2), "+v"(b2));
        pa[cb][c].w[0] = a1; pa[cb][c].w[1] = a2;
        pa[cb][c].w[2] = b1; pa[cb][c].w[3] = b2;
      }
    }

    // ---- PV: O[q][d] ; A = P (regs), B = V from LDS (col d = l31)
    __builtin_amdgcn_s_setprio(1);
#pragma unroll
    for (int cb = 0; cb < 2; ++cb)
#pragma unroll
      for (int c = 0; c < 2; ++c)
#pragma unroll
        for (int db = 0; db < 2; ++db) {
          int vrow = db * 32 + l31;
          int ch = (cb * 4 + c * 2 + hi) ^ (l31 & 7);
          bf16x8 vf = *reinterpret_cast<const bf16x8*>(&lV[cur][vrow * 64 + ch * 8]);
          oacc[db] = __builtin_amdgcn_mfma_f32_32x32x16_bf16(pa[cb][c].v, vf, oacc[db], 0, 0, 0);
        }
    __builtin_amdgcn_s_setprio(0);
    __builtin_amdgcn_s_barrier();
    cur ^= 1;
  }

  // ---- epilogue: combine denom halves, normalize, store
  dn += __shfl_xor(dn, 32);
#pragma unroll
  for (int r = 0; r < 16; ++r) {
    int qrel = (r & 3) + 8 * (r >> 2) + 4 * hi;
    float dfull = __shfl(dn, qrel);
    float inv = __builtin_amdgcn_rcpf(dfull);
    int q = q0w + qrel;
#pragma unroll
    for (int db = 0; db < 2; ++db) {
      int d = db * 32 + l31;
      Out[(size_t)(b * SEQ + q) * EMB + h * 64 + d] = f2bf(oacc[db][r] * inv);
    }
  }
}

// ---------------- launch ----------------
extern "C" void kernel_launch(void* const* d_in, const int* in_sizes, int n_in,
                              void* d_out, int out_size, void* d_ws, size_t ws_size,
                              hipStream_t stream) {
  const float* x = (const float*)d_in[0];
  const float* bqkv = (const float*)d_in[2];
  const float* bout = (const float*)d_in[4];
  float* out = (float*)d_out;

  char* ws = (char*)d_ws;
  size_t off = 0;
  auto alloc = [&](size_t bytes) {
    void* p = ws + off;
    off += (bytes + 255) & ~(size_t)255;
    return p;
  };
  u16* xb    = (u16*)alloc((size_t)MTOT * EMB * 2);
  u16* wqkvb = (u16*)alloc((size_t)3 * EMB * EMB * 2);
  u16* woutb = (u16*)alloc((size_t)EMB * EMB * 2);
  u16* qkv   = (u16*)alloc((size_t)MTOT * 3 * EMB * 2);
  u16* Qb    = (u16*)alloc((size_t)64 * SEQ * HD * 2);
  u16* Kb    = (u16*)alloc((size_t)64 * SEQ * HD * 2);
  u16* Vtb   = (u16*)alloc((size_t)64 * HD * SEQ * 2);
  u16* aout  = (u16*)alloc((size_t)MTOT * EMB * 2);
  float* tab = (float*)alloc((size_t)2 * SEQ * 32 * 4);
  (void)ws_size; (void)in_sizes; (void)n_in; (void)out_size;

  cast_kernel<<<2048, 256, 0, stream>>>(x, xb, MTOT * EMB / 4);
  cast_kernel<<<1024, 256, 0, stream>>>((const float*)d_in[1], wqkvb, 3 * EMB * EMB / 4);
  cast_kernel<<<512, 256, 0, stream>>>((const float*)d_in[3], woutb, EMB * EMB / 4);
  rope_table_kernel<<<(SEQ * 32 + 255) / 256, 256, 0, stream>>>(tab);

  gemm_bt<false><<<64 * 24, 256, 0, stream>>>(xb, wqkvb, bqkv, qkv, 3 * EMB, 24);
  rope_scatter<<<64 * 32, 256, 0, stream>>>(qkv, tab, Qb, Kb, Vtb);
  attn_kernel<<<64 * 16, 256, 0, stream>>>(Qb, Kb, Vtb, aout);
  gemm_bt<true><<<64 * 8, 256, 0, stream>>>(aout, woutb, bout, out, EMB, 8);
}

// Round 8
// 194.128 us; speedup vs baseline: 1.0737x; 1.0275x over previous
//
#include <hip/hip_runtime.h>
#include <hip/hip_bf16.h>
#include <cstdint>
#include <cstddef>

#define SEQ 2048
#define NBATCH 4
#define EMB 1024
#define NH 16
#define HD 64
#define MTOT (NBATCH * SEQ)   // 8192

typedef __attribute__((ext_vector_type(8))) short bf16x8;
typedef __attribute__((ext_vector_type(4))) float f32x4;
typedef __attribute__((ext_vector_type(16))) float f32x16;
typedef unsigned short u16;
typedef unsigned int u32;

__device__ __forceinline__ float bf2f(u16 v) {
  union { u32 u; float f; } c; c.u = ((u32)v) << 16; return c.f;
}
__device__ __forceinline__ u16 f2bf(float f) {
  union { float f; u32 u; } c; c.f = f;
  u32 u = c.u;
  return (u16)((u + 0x7FFFu + ((u >> 16) & 1u)) >> 16);
}
__device__ __forceinline__ u32 f2u(float f) {
  union { float f; u32 u; } c; c.f = f; return c.u;
}

// ---------------- cast fp32 -> bf16 (vectorized) ----------------
__global__ void cast_kernel(const float* __restrict__ in, u16* __restrict__ out, int n4) {
  int stride = gridDim.x * blockDim.x;
  for (int i = blockIdx.x * blockDim.x + threadIdx.x; i < n4; i += stride) {
    float4 v = reinterpret_cast<const float4*>(in)[i];
    ushort4 o;
    o.x = f2bf(v.x); o.y = f2bf(v.y); o.z = f2bf(v.z); o.w = f2bf(v.w);
    reinterpret_cast<ushort4*>(out)[i] = o;
  }
}

// ---------------- RoPE table [SEQ][32] of (cos,sin) float2 ----------------
__global__ void rope_table2_kernel(float* __restrict__ tab2) {
  int i = blockIdx.x * blockDim.x + threadIdx.x;
  if (i >= SEQ * 32) return;
  int n = i >> 5, j = i & 31;
  float invf = 1.0f / powf(10000.0f, (float)(2 * j) / 64.0f);
  float ang = (float)n * invf;
  tab2[2 * i] = cosf(ang);
  tab2[2 * i + 1] = sinf(ang);
}

// ---------------- async global->LDS helper (16B) ----------------
__device__ __forceinline__ void gld_lds16(const u16* g, u16* l) {
  __builtin_amdgcn_global_load_lds((const __attribute__((address_space(1))) void*)g,
                                   (__attribute__((address_space(3))) void*)l, 16, 0, 0);
}

// ---------------- GEMM: C[M,N] = A[M,K] * Bw[N,K]^T + bias (out-proj, fp32 out) ----------------
__global__ __launch_bounds__(256, 2)
void gemm_bt_f32(const u16* __restrict__ A, const u16* __restrict__ Bw,
                 const float* __restrict__ bias, float* __restrict__ Cout,
                 int N, int tiles_n) {
  __shared__ u16 lA[128 * 64];
  __shared__ u16 lB[128 * 64];
  const int K = 1024;
  int bm = blockIdx.x / tiles_n;
  int bn = blockIdx.x % tiles_n;
  int t = threadIdx.x;
  int wave = t >> 6, lane = t & 63;
  int wm = wave >> 1, wn = wave & 1;
  int l15 = lane & 15, l4 = lane >> 4;

  f32x4 acc[4][4];
#pragma unroll
  for (int i = 0; i < 4; ++i)
#pragma unroll
    for (int j = 0; j < 4; ++j) acc[i][j] = (f32x4){0.f, 0.f, 0.f, 0.f};

  int su[4], sr[4], sc[4];
#pragma unroll
  for (int i = 0; i < 4; ++i) {
    int u = (i * 4 + wave) * 64 + lane;
    su[i] = u;
    sr[i] = u >> 3;
    sc[i] = (u & 7) ^ (sr[i] & 7);
  }

  for (int kt = 0; kt < K / 64; ++kt) {
    if (kt) __syncthreads();
#pragma unroll
    for (int i = 0; i < 4; ++i) {
      gld_lds16(A + (size_t)(bm * 128 + sr[i]) * K + kt * 64 + sc[i] * 8, &lA[su[i] * 8]);
      gld_lds16(Bw + (size_t)(bn * 128 + sr[i]) * K + kt * 64 + sc[i] * 8, &lB[su[i] * 8]);
    }
    __syncthreads();
#pragma unroll
    for (int ks = 0; ks < 2; ++ks) {
      bf16x8 af[4], bfr[4];
#pragma unroll
      for (int mb = 0; mb < 4; ++mb) {
        int r = wm * 64 + mb * 16 + l15;
        int cc = (ks * 4 + l4) ^ (r & 7);
        af[mb] = *reinterpret_cast<const bf16x8*>(&lA[r * 64 + cc * 8]);
      }
#pragma unroll
      for (int nb = 0; nb < 4; ++nb) {
        int r = wn * 64 + nb * 16 + l15;
        int cc = (ks * 4 + l4) ^ (r & 7);
        bfr[nb] = *reinterpret_cast<const bf16x8*>(&lB[r * 64 + cc * 8]);
      }
#pragma unroll
      for (int mb = 0; mb < 4; ++mb)
#pragma unroll
        for (int nb = 0; nb < 4; ++nb)
          acc[mb][nb] = __builtin_amdgcn_mfma_f32_16x16x32_bf16(af[mb], bfr[nb], acc[mb][nb], 0, 0, 0);
    }
  }

#pragma unroll
  for (int mb = 0; mb < 4; ++mb)
#pragma unroll
    for (int nb = 0; nb < 4; ++nb) {
      int row0 = bm * 128 + wm * 64 + mb * 16 + l4 * 4;
      int col = bn * 128 + wn * 64 + nb * 16 + l15;
      float bv = bias[col];
#pragma unroll
      for (int r = 0; r < 4; ++r)
        Cout[(size_t)(row0 + r) * N + col] = acc[mb][nb][r] + bv;
    }
}

// ---------------- fused QKV GEMM + bias + RoPE + scatter ----------------
// C[M,3072] = x_bf16 @ W_qkv^T + b ; per 128-col tile the (d, d^32) RoPE pair is in-thread
// (cols l15, l15+16, l15+32, l15+48 of one 64-col head). q gets scale*log2e folded.
// Outputs: Q,K [BH][SEQ][64] bf16 ; V transposed [BH][64][SEQ] bf16 (aligned ushort4 runs).
__global__ __launch_bounds__(256, 2)
void gemm_qkv_rope(const u16* __restrict__ A, const u16* __restrict__ Bw,
                   const float* __restrict__ bias, const float* __restrict__ tab2,
                   u16* __restrict__ Qb, u16* __restrict__ Kb, u16* __restrict__ Vtb) {
  __shared__ u16 lA[128 * 64];
  __shared__ u16 lB[128 * 64];
  const int K = 1024, tiles_n = 24;
  int bm = blockIdx.x / tiles_n;
  int bn = blockIdx.x % tiles_n;
  int t = threadIdx.x;
  int wave = t >> 6, lane = t & 63;
  int wm = wave >> 1, wn = wave & 1;
  int l15 = lane & 15, l4 = lane >> 4;

  f32x4 acc[4][4];
#pragma unroll
  for (int i = 0; i < 4; ++i)
#pragma unroll
    for (int j = 0; j < 4; ++j) acc[i][j] = (f32x4){0.f, 0.f, 0.f, 0.f};

  int su[4], sr[4], sc[4];
#pragma unroll
  for (int i = 0; i < 4; ++i) {
    int u = (i * 4 + wave) * 64 + lane;
    su[i] = u;
    sr[i] = u >> 3;
    sc[i] = (u & 7) ^ (sr[i] & 7);
  }

  for (int kt = 0; kt < K / 64; ++kt) {
    if (kt) __syncthreads();
#pragma unroll
    for (int i = 0; i < 4; ++i) {
      gld_lds16(A + (size_t)(bm * 128 + sr[i]) * K + kt * 64 + sc[i] * 8, &lA[su[i] * 8]);
      gld_lds16(Bw + (size_t)(bn * 128 + sr[i]) * K + kt * 64 + sc[i] * 8, &lB[su[i] * 8]);
    }
    __syncthreads();
#pragma unroll
    for (int ks = 0; ks < 2; ++ks) {
      bf16x8 af[4], bfr[4];
#pragma unroll
      for (int mb = 0; mb < 4; ++mb) {
        int r = wm * 64 + mb * 16 + l15;
        int cc = (ks * 4 + l4) ^ (r & 7);
        af[mb] = *reinterpret_cast<const bf16x8*>(&lA[r * 64 + cc * 8]);
      }
#pragma unroll
      for (int nb = 0; nb < 4; ++nb) {
        int r = wn * 64 + nb * 16 + l15;
        int cc = (ks * 4 + l4) ^ (r & 7);
        bfr[nb] = *reinterpret_cast<const bf16x8*>(&lB[r * 64 + cc * 8]);
      }
#pragma unroll
      for (int mb = 0; mb < 4; ++mb)
#pragma unroll
        for (int nb = 0; nb < 4; ++nb)
          acc[mb][nb] = __builtin_amdgcn_mfma_f32_16x16x32_bf16(af[mb], bfr[nb], acc[mb][nb], 0, 0, 0);
    }
  }

  // ---- fused epilogue ----
  int type = bn >> 3;            // 0=q, 1=k, 2=v
  int h = (bn * 2 + wn) & 15;    // head
  int colbase = bn * 128 + wn * 64;
  float bv[4];
#pragma unroll
  for (int nb = 0; nb < 4; ++nb) bv[nb] = bias[colbase + nb * 16 + l15];

  if (type < 2) {
    u16* dst0 = (type == 0) ? Qb : Kb;
    float qs = (type == 0) ? 0.1803368801111163f : 1.0f;  // (1/8)*log2(e) folded into q
#pragma unroll
    for (int mb = 0; mb < 4; ++mb) {
      int row0 = bm * 128 + wm * 64 + mb * 16 + l4 * 4;
#pragma unroll
      for (int r = 0; r < 4; ++r) {
        int row = row0 + r;
        int bb = row >> 11, nl = row & 2047;
        const float* tp = tab2 + (size_t)nl * 64;
        float2 cs  = *reinterpret_cast<const float2*>(tp + 2 * l15);
        float2 cs2 = *reinterpret_cast<const float2*>(tp + 2 * (16 + l15));
        float a0 = acc[mb][0][r] + bv[0];
        float a1 = acc[mb][1][r] + bv[1];
        float a2 = acc[mb][2][r] + bv[2];
        float a3 = acc[mb][3][r] + bv[3];
        float o0 = (a0 * cs.x  - a2 * cs.y)  * qs;
        float o2 = (a2 * cs.x  + a0 * cs.y)  * qs;
        float o1 = (a1 * cs2.x - a3 * cs2.y) * qs;
        float o3 = (a3 * cs2.x + a1 * cs2.y) * qs;
        u16* dst = dst0 + ((size_t)(bb * 16 + h) * SEQ + nl) * 64;
        dst[l15]      = f2bf(o0);
        dst[16 + l15] = f2bf(o1);
        dst[32 + l15] = f2bf(o2);
        dst[48 + l15] = f2bf(o3);
      }
    }
  } else {
#pragma unroll
    for (int mb = 0; mb < 4; ++mb) {
      int row0 = bm * 128 + wm * 64 + mb * 16 + l4 * 4;
      int bb = row0 >> 11, nl0 = row0 & 2047;
#pragma unroll
      for (int nb = 0; nb < 4; ++nb) {
        int d = nb * 16 + l15;
        ushort4 pk;
        pk.x = f2bf(acc[mb][nb][0] + bv[nb]);
        pk.y = f2bf(acc[mb][nb][1] + bv[nb]);
        pk.z = f2bf(acc[mb][nb][2] + bv[nb]);
        pk.w = f2bf(acc[mb][nb][3] + bv[nb]);
        *reinterpret_cast<ushort4*>(&Vtb[((size_t)(bb * 16 + h) * 64 + d) * SEQ + nl0]) = pk;
      }
    }
  }
}

// ---------------- attention v8: chunk-major LDS (conflict-free b128 reads) ----------------
// 256 threads = 4 waves, 32 q-rows/wave; grid = 64 heads * 16 q-tiles = 1024 blocks = 4/CU.
// LDS tiles stored [8 chunks][64 rows][8 bf16]: QK/PV column-slice reads become
// lane-consecutive 16B -> zero bank conflicts, no XOR addressing.
__global__ __launch_bounds__(256, 4)
void attn_kernel(const u16* __restrict__ Q, const u16* __restrict__ Kk,
                 const u16* __restrict__ Vt, u16* __restrict__ Out) {
  int bid = blockIdx.x;
  int swz = (bid & 7) * 128 + (bid >> 3);  // XCD-chunked: each XCD owns 8 heads (4MB = L2)
  int bh = swz >> 4;
  int qt = swz & 15;
  int b = bh >> 4, h = bh & 15;
  int t = threadIdx.x;
  int wave = t >> 6, lane = t & 63;
  int l31 = lane & 31, hi = lane >> 5;

  __shared__ u16 lK[2][512 * 8];
  __shared__ u16 lV[2][512 * 8];

  const u16* Qh = Q + (size_t)bh * SEQ * 64;
  const u16* Kh = Kk + (size_t)bh * SEQ * 64;
  const u16* Vh = Vt + (size_t)bh * 64 * SEQ;
  int q0w = qt * 128 + wave * 32;

  // Q fragments (B-operand): col q = l31, k-dim elems d = dc*16 + hi*8 + j
  bf16x8 qf[4];
#pragma unroll
  for (int dc = 0; dc < 4; ++dc)
    qf[dc] = *reinterpret_cast<const bf16x8*>(
        &Qh[(size_t)(q0w + l31) * 64 + dc * 16 + hi * 8]);

  f32x16 oacc[2];
#pragma unroll
  for (int db = 0; db < 2; ++db)
#pragma unroll
    for (int r = 0; r < 16; ++r) oacc[db][r] = 0.f;
  float dn = 0.f;

  // staging: chunk-major. K slot (dchunk=u>>6, krow=u&63) <- K[kt*64+krow][dchunk*8..+8]
  //          V slot (nchunk=u>>6, d=u&63)   <- V[d][kt*64 + nchunk*8..+8]
  auto stage = [&](int buf, int kt) {
#pragma unroll
    for (int p = 0; p < 2; ++p) {
      int u = p * 256 + t;
      gld_lds16(Kh + (size_t)(kt * 64 + (u & 63)) * 64 + (u >> 6) * 8, &lK[buf][u * 8]);
      gld_lds16(Vh + (size_t)(u & 63) * SEQ + kt * 64 + (u >> 6) * 8, &lV[buf][u * 8]);
    }
  };

  union PF { u32 w[4]; bf16x8 v; };
  int cur = 0;
  stage(0, 0);
  for (int kt = 0; kt < SEQ / 64; ++kt) {
    if (kt + 1 < SEQ / 64) {
      stage(cur ^ 1, kt + 1);
      asm volatile("s_waitcnt vmcnt(4)" ::: "memory");  // current tile's 4 loads done; next in flight
    } else {
      asm volatile("s_waitcnt vmcnt(0)" ::: "memory");
    }
    __builtin_amdgcn_s_barrier();

    // ---- QK^T swapped: S^T[k][q] ; lane: q = l31, k = cb*32 + (r&3)+8*(r>>2)+4*hi
    f32x16 s[2];
#pragma unroll
    for (int cb = 0; cb < 2; ++cb)
#pragma unroll
      for (int r = 0; r < 16; ++r) s[cb][r] = 0.f;
    __builtin_amdgcn_s_setprio(1);
#pragma unroll
    for (int cb = 0; cb < 2; ++cb) {
#pragma unroll
      for (int dc = 0; dc < 4; ++dc) {
        bf16x8 kf = *reinterpret_cast<const bf16x8*>(
            &lK[cur][(((dc * 2 + hi) << 6) + cb * 32 + l31) * 8]);
        s[cb] = __builtin_amdgcn_mfma_f32_32x32x16_bf16(kf, qf[dc], s[cb], 0, 0, 0);
      }
    }
    __builtin_amdgcn_s_setprio(0);

    // ---- softmax in-register: exp2 (denom unrounded), round-half-up + v_perm pack to bf16
    PF pa[2][2];  // [cb][c(16-k chunk)]
#pragma unroll
    for (int cb = 0; cb < 2; ++cb) {
#pragma unroll
      for (int r = 0; r < 16; ++r) {
        float e = __builtin_amdgcn_exp2f(s[cb][r]);
        s[cb][r] = e;
        dn += e;
      }
#pragma unroll
      for (int c = 0; c < 2; ++c) {
        u32 u0 = f2u(s[cb][8 * c + 0]) + 0x8000u;
        u32 u1 = f2u(s[cb][8 * c + 1]) + 0x8000u;
        u32 u2 = f2u(s[cb][8 * c + 2]) + 0x8000u;
        u32 u3 = f2u(s[cb][8 * c + 3]) + 0x8000u;
        u32 u4 = f2u(s[cb][8 * c + 4]) + 0x8000u;
        u32 u5 = f2u(s[cb][8 * c + 5]) + 0x8000u;
        u32 u6 = f2u(s[cb][8 * c + 6]) + 0x8000u;
        u32 u7 = f2u(s[cb][8 * c + 7]) + 0x8000u;
        u32 a1 = __builtin_amdgcn_perm(u1, u0, 0x07060302);  // bf16(e1)<<16 | bf16(e0)
        u32 a2 = __builtin_amdgcn_perm(u3, u2, 0x07060302);
        u32 b1 = __builtin_amdgcn_perm(u5, u4, 0x07060302);
        u32 b2 = __builtin_amdgcn_perm(u7, u6, 0x07060302);
        asm("v_permlane32_swap_b32 %0, %1" : "+v"(a1), "+v"(b1));
        asm("v_permlane32_swap_b32 %0, %1" : "+v"(a2), "+v"(b2));
        pa[cb][c].w[0] = a1; pa[cb][c].w[1] = a2;
        pa[cb][c].w[2] = b1; pa[cb][c].w[3] = b2;
      }
    }

    // ---- PV: O[q][d] ; A = P (regs), B = V from LDS (col d = l31)
    __builtin_amdgcn_s_setprio(1);
#pragma unroll
    for (int cb = 0; cb < 2; ++cb)
#pragma unroll
      for (int c = 0; c < 2; ++c)
#pragma unroll
        for (int db = 0; db < 2; ++db) {
          bf16x8 vf = *reinterpret_cast<const bf16x8*>(
              &lV[cur][(((cb * 4 + c * 2 + hi) << 6) + db * 32 + l31) * 8]);
          oacc[db] = __builtin_amdgcn_mfma_f32_32x32x16_bf16(pa[cb][c].v, vf, oacc[db], 0, 0, 0);
        }
    __builtin_amdgcn_s_setprio(0);
    __builtin_amdgcn_s_barrier();
    cur ^= 1;
  }

  // ---- epilogue: combine denom halves, normalize, store
  dn += __shfl_xor(dn, 32);
#pragma unroll
  for (int r = 0; r < 16; ++r) {
    int qrel = (r & 3) + 8 * (r >> 2) + 4 * hi;
    float dfull = __shfl(dn, qrel);
    float inv = __builtin_amdgcn_rcpf(dfull);
    int q = q0w + qrel;
#pragma unroll
    for (int db = 0; db < 2; ++db) {
      int d = db * 32 + l31;
      Out[(size_t)(b * SEQ + q) * EMB + h * 64 + d] = f2bf(oacc[db][r] * inv);
    }
  }
}

// ---------------- launch ----------------
extern "C" void kernel_launch(void* const* d_in, const int* in_sizes, int n_in,
                              void* d_out, int out_size, void* d_ws, size_t ws_size,
                              hipStream_t stream) {
  const float* x = (const float*)d_in[0];
  const float* bqkv = (const float*)d_in[2];
  const float* bout = (const float*)d_in[4];
  float* out = (float*)d_out;

  char* ws = (char*)d_ws;
  size_t off = 0;
  auto alloc = [&](size_t bytes) {
    void* p = ws + off;
    off += (bytes + 255) & ~(size_t)255;
    return p;
  };
  u16* xb    = (u16*)alloc((size_t)MTOT * EMB * 2);
  u16* wqkvb = (u16*)alloc((size_t)3 * EMB * EMB * 2);
  u16* woutb = (u16*)alloc((size_t)EMB * EMB * 2);
  u16* Qb    = (u16*)alloc((size_t)64 * SEQ * HD * 2);
  u16* Kb    = (u16*)alloc((size_t)64 * SEQ * HD * 2);
  u16* Vtb   = (u16*)alloc((size_t)64 * HD * SEQ * 2);
  u16* aout  = (u16*)alloc((size_t)MTOT * EMB * 2);
  float* tab2 = (float*)alloc((size_t)SEQ * 32 * 2 * 4);
  (void)ws_size; (void)in_sizes; (void)n_in; (void)out_size;

  cast_kernel<<<2048, 256, 0, stream>>>(x, xb, MTOT * EMB / 4);
  cast_kernel<<<1024, 256, 0, stream>>>((const float*)d_in[1], wqkvb, 3 * EMB * EMB / 4);
  cast_kernel<<<512, 256, 0, stream>>>((const float*)d_in[3], woutb, EMB * EMB / 4);
  rope_table2_kernel<<<(SEQ * 32 + 255) / 256, 256, 0, stream>>>(tab2);

  gemm_qkv_rope<<<64 * 24, 256, 0, stream>>>(xb, wqkvb, bqkv, tab2, Qb, Kb, Vtb);
  attn_kernel<<<64 * 16, 256, 0, stream>>>(Qb, Kb, Vtb, aout);
  gemm_bt_f32<<<64 * 8, 256, 0, stream>>>(aout, woutb, bout, out, EMB, 8);
}

// Round 9
// 187.895 us; speedup vs baseline: 1.1093x; 1.0332x over previous
//
#include <hip/hip_runtime.h>
#include <hip/hip_bf16.h>
#include <cstdint>
#include <cstddef>

#define SEQ 2048
#define NBATCH 4
#define EMB 1024
#define NH 16
#define HD 64
#define MTOT (NBATCH * SEQ)   // 8192

typedef __attribute__((ext_vector_type(8))) short bf16x8;
typedef __attribute__((ext_vector_type(4))) float f32x4;
typedef __attribute__((ext_vector_type(16))) float f32x16;
typedef unsigned short u16;
typedef unsigned int u32;

__device__ __forceinline__ float bf2f(u16 v) {
  union { u32 u; float f; } c; c.u = ((u32)v) << 16; return c.f;
}
__device__ __forceinline__ u16 f2bf(float f) {
  union { float f; u32 u; } c; c.f = f;
  u32 u = c.u;
  return (u16)((u + 0x7FFFu + ((u >> 16) & 1u)) >> 16);
}
__device__ __forceinline__ u32 f2u(float f) {
  union { float f; u32 u; } c; c.f = f; return c.u;
}

// ---------------- cast fp32 -> bf16 (vectorized) ----------------
__global__ void cast_kernel(const float* __restrict__ in, u16* __restrict__ out, int n4) {
  int stride = gridDim.x * blockDim.x;
  for (int i = blockIdx.x * blockDim.x + threadIdx.x; i < n4; i += stride) {
    float4 v = reinterpret_cast<const float4*>(in)[i];
    ushort4 o;
    o.x = f2bf(v.x); o.y = f2bf(v.y); o.z = f2bf(v.z); o.w = f2bf(v.w);
    reinterpret_cast<ushort4*>(out)[i] = o;
  }
}

// ---------------- RoPE table [SEQ][32] of (cos,sin) float2 ----------------
__global__ void rope_table2_kernel(float* __restrict__ tab2) {
  int i = blockIdx.x * blockDim.x + threadIdx.x;
  if (i >= SEQ * 32) return;
  int n = i >> 5, j = i & 31;
  float invf = 1.0f / powf(10000.0f, (float)(2 * j) / 64.0f);
  float ang = (float)n * invf;
  tab2[2 * i] = cosf(ang);
  tab2[2 * i + 1] = sinf(ang);
}

// ---------------- async global->LDS helper (16B) ----------------
__device__ __forceinline__ void gld_lds16(const u16* g, u16* l) {
  __builtin_amdgcn_global_load_lds((const __attribute__((address_space(1))) void*)g,
                                   (__attribute__((address_space(3))) void*)l, 16, 0, 0);
}

// ---------------- GEMM: C[M,N] = A[M,K] * Bw[N,K]^T + bias (out-proj, fp32 out) ----------------
__global__ __launch_bounds__(256, 2)
void gemm_bt_f32(const u16* __restrict__ A, const u16* __restrict__ Bw,
                 const float* __restrict__ bias, float* __restrict__ Cout,
                 int N, int tiles_n) {
  __shared__ u16 lA[128 * 64];
  __shared__ u16 lB[128 * 64];
  const int K = 1024;
  int bm = blockIdx.x / tiles_n;
  int bn = blockIdx.x % tiles_n;
  int t = threadIdx.x;
  int wave = t >> 6, lane = t & 63;
  int wm = wave >> 1, wn = wave & 1;
  int l15 = lane & 15, l4 = lane >> 4;

  f32x4 acc[4][4];
#pragma unroll
  for (int i = 0; i < 4; ++i)
#pragma unroll
    for (int j = 0; j < 4; ++j) acc[i][j] = (f32x4){0.f, 0.f, 0.f, 0.f};

  int su[4], sr[4], sc[4];
#pragma unroll
  for (int i = 0; i < 4; ++i) {
    int u = (i * 4 + wave) * 64 + lane;
    su[i] = u;
    sr[i] = u >> 3;
    sc[i] = (u & 7) ^ (sr[i] & 7);
  }

  for (int kt = 0; kt < K / 64; ++kt) {
    if (kt) __syncthreads();
#pragma unroll
    for (int i = 0; i < 4; ++i) {
      gld_lds16(A + (size_t)(bm * 128 + sr[i]) * K + kt * 64 + sc[i] * 8, &lA[su[i] * 8]);
      gld_lds16(Bw + (size_t)(bn * 128 + sr[i]) * K + kt * 64 + sc[i] * 8, &lB[su[i] * 8]);
    }
    __syncthreads();
#pragma unroll
    for (int ks = 0; ks < 2; ++ks) {
      bf16x8 af[4], bfr[4];
#pragma unroll
      for (int mb = 0; mb < 4; ++mb) {
        int r = wm * 64 + mb * 16 + l15;
        int cc = (ks * 4 + l4) ^ (r & 7);
        af[mb] = *reinterpret_cast<const bf16x8*>(&lA[r * 64 + cc * 8]);
      }
#pragma unroll
      for (int nb = 0; nb < 4; ++nb) {
        int r = wn * 64 + nb * 16 + l15;
        int cc = (ks * 4 + l4) ^ (r & 7);
        bfr[nb] = *reinterpret_cast<const bf16x8*>(&lB[r * 64 + cc * 8]);
      }
#pragma unroll
      for (int mb = 0; mb < 4; ++mb)
#pragma unroll
        for (int nb = 0; nb < 4; ++nb)
          acc[mb][nb] = __builtin_amdgcn_mfma_f32_16x16x32_bf16(af[mb], bfr[nb], acc[mb][nb], 0, 0, 0);
    }
  }

#pragma unroll
  for (int mb = 0; mb < 4; ++mb)
#pragma unroll
    for (int nb = 0; nb < 4; ++nb) {
      int row0 = bm * 128 + wm * 64 + mb * 16 + l4 * 4;
      int col = bn * 128 + wn * 64 + nb * 16 + l15;
      float bv = bias[col];
#pragma unroll
      for (int r = 0; r < 4; ++r)
        Cout[(size_t)(row0 + r) * N + col] = acc[mb][nb][r] + bv;
    }
}

// ---------------- fused QKV GEMM + bias + RoPE + scatter ----------------
__global__ __launch_bounds__(256, 2)
void gemm_qkv_rope(const u16* __restrict__ A, const u16* __restrict__ Bw,
                   const float* __restrict__ bias, const float* __restrict__ tab2,
                   u16* __restrict__ Qb, u16* __restrict__ Kb, u16* __restrict__ Vtb) {
  __shared__ u16 lA[128 * 64];
  __shared__ u16 lB[128 * 64];
  const int K = 1024, tiles_n = 24;
  int bm = blockIdx.x / tiles_n;
  int bn = blockIdx.x % tiles_n;
  int t = threadIdx.x;
  int wave = t >> 6, lane = t & 63;
  int wm = wave >> 1, wn = wave & 1;
  int l15 = lane & 15, l4 = lane >> 4;

  f32x4 acc[4][4];
#pragma unroll
  for (int i = 0; i < 4; ++i)
#pragma unroll
    for (int j = 0; j < 4; ++j) acc[i][j] = (f32x4){0.f, 0.f, 0.f, 0.f};

  int su[4], sr[4], sc[4];
#pragma unroll
  for (int i = 0; i < 4; ++i) {
    int u = (i * 4 + wave) * 64 + lane;
    su[i] = u;
    sr[i] = u >> 3;
    sc[i] = (u & 7) ^ (sr[i] & 7);
  }

  for (int kt = 0; kt < K / 64; ++kt) {
    if (kt) __syncthreads();
#pragma unroll
    for (int i = 0; i < 4; ++i) {
      gld_lds16(A + (size_t)(bm * 128 + sr[i]) * K + kt * 64 + sc[i] * 8, &lA[su[i] * 8]);
      gld_lds16(Bw + (size_t)(bn * 128 + sr[i]) * K + kt * 64 + sc[i] * 8, &lB[su[i] * 8]);
    }
    __syncthreads();
#pragma unroll
    for (int ks = 0; ks < 2; ++ks) {
      bf16x8 af[4], bfr[4];
#pragma unroll
      for (int mb = 0; mb < 4; ++mb) {
        int r = wm * 64 + mb * 16 + l15;
        int cc = (ks * 4 + l4) ^ (r & 7);
        af[mb] = *reinterpret_cast<const bf16x8*>(&lA[r * 64 + cc * 8]);
      }
#pragma unroll
      for (int nb = 0; nb < 4; ++nb) {
        int r = wn * 64 + nb * 16 + l15;
        int cc = (ks * 4 + l4) ^ (r & 7);
        bfr[nb] = *reinterpret_cast<const bf16x8*>(&lB[r * 64 + cc * 8]);
      }
#pragma unroll
      for (int mb = 0; mb < 4; ++mb)
#pragma unroll
        for (int nb = 0; nb < 4; ++nb)
          acc[mb][nb] = __builtin_amdgcn_mfma_f32_16x16x32_bf16(af[mb], bfr[nb], acc[mb][nb], 0, 0, 0);
    }
  }

  // ---- fused epilogue ----
  int type = bn >> 3;            // 0=q, 1=k, 2=v
  int h = (bn * 2 + wn) & 15;    // head
  int colbase = bn * 128 + wn * 64;
  float bv[4];
#pragma unroll
  for (int nb = 0; nb < 4; ++nb) bv[nb] = bias[colbase + nb * 16 + l15];

  if (type < 2) {
    u16* dst0 = (type == 0) ? Qb : Kb;
    float qs = (type == 0) ? 0.1803368801111163f : 1.0f;  // (1/8)*log2(e) folded into q
#pragma unroll
    for (int mb = 0; mb < 4; ++mb) {
      int row0 = bm * 128 + wm * 64 + mb * 16 + l4 * 4;
#pragma unroll
      for (int r = 0; r < 4; ++r) {
        int row = row0 + r;
        int bb = row >> 11, nl = row & 2047;
        const float* tp = tab2 + (size_t)nl * 64;
        float2 cs  = *reinterpret_cast<const float2*>(tp + 2 * l15);
        float2 cs2 = *reinterpret_cast<const float2*>(tp + 2 * (16 + l15));
        float a0 = acc[mb][0][r] + bv[0];
        float a1 = acc[mb][1][r] + bv[1];
        float a2 = acc[mb][2][r] + bv[2];
        float a3 = acc[mb][3][r] + bv[3];
        float o0 = (a0 * cs.x  - a2 * cs.y)  * qs;
        float o2 = (a2 * cs.x  + a0 * cs.y)  * qs;
        float o1 = (a1 * cs2.x - a3 * cs2.y) * qs;
        float o3 = (a3 * cs2.x + a1 * cs2.y) * qs;
        u16* dst = dst0 + ((size_t)(bb * 16 + h) * SEQ + nl) * 64;
        dst[l15]      = f2bf(o0);
        dst[16 + l15] = f2bf(o1);
        dst[32 + l15] = f2bf(o2);
        dst[48 + l15] = f2bf(o3);
      }
    }
  } else {
#pragma unroll
    for (int mb = 0; mb < 4; ++mb) {
      int row0 = bm * 128 + wm * 64 + mb * 16 + l4 * 4;
      int bb = row0 >> 11, nl0 = row0 & 2047;
#pragma unroll
      for (int nb = 0; nb < 4; ++nb) {
        int d = nb * 16 + l15;
        ushort4 pk;
        pk.x = f2bf(acc[mb][nb][0] + bv[nb]);
        pk.y = f2bf(acc[mb][nb][1] + bv[nb]);
        pk.z = f2bf(acc[mb][nb][2] + bv[nb]);
        pk.w = f2bf(acc[mb][nb][3] + bv[nb]);
        *reinterpret_cast<ushort4*>(&Vtb[((size_t)(bb * 16 + h) * 64 + d) * SEQ + nl0]) = pk;
      }
    }
  }
}

// ---------------- attention v9: reg-staged padded chunk-major LDS (T14 split) ----------------
// 256 threads = 4 waves, 32 q-rows/wave; grid = 1024 blocks = 4/CU.
// LDS slot (chunk c, row r) at 16B-addr c*65 + r: fixed-chunk reads are lane-consecutive
// (0 conflicts); ds_write (r=t>>3, c=t&7) is bank-balanced ((65c+r)%8 = (c+r)%8 uniform).
// Staging: coalesced global_load_dwordx4 issued BEFORE compute; ds_write after (latency hidden).
__global__ __launch_bounds__(256, 4)
void attn_kernel(const u16* __restrict__ Q, const u16* __restrict__ Kk,
                 const u16* __restrict__ Vt, u16* __restrict__ Out) {
  int bid = blockIdx.x;
  int swz = (bid & 7) * 128 + (bid >> 3);  // XCD-chunked: each XCD owns 8 heads (4MB = L2)
  int bh = swz >> 4;
  int qt = swz & 15;
  int b = bh >> 4, h = bh & 15;
  int t = threadIdx.x;
  int wave = t >> 6, lane = t & 63;
  int l31 = lane & 31, hi = lane >> 5;

  __shared__ u16 lK[2][520 * 8];  // 8 chunks * 65 (64 rows + 1 pad) 16B slots
  __shared__ u16 lV[2][520 * 8];

  const u16* Qh = Q + (size_t)bh * SEQ * 64;
  const u16* Kh = Kk + (size_t)bh * SEQ * 64;
  const u16* Vh = Vt + (size_t)bh * 64 * SEQ;
  int q0w = qt * 128 + wave * 32;

  // Q fragments (B-operand): col q = l31, k-dim elems d = dc*16 + hi*8 + j
  bf16x8 qf[4];
#pragma unroll
  for (int dc = 0; dc < 4; ++dc)
    qf[dc] = *reinterpret_cast<const bf16x8*>(
        &Qh[(size_t)(q0w + l31) * 64 + dc * 16 + hi * 8]);

  f32x16 oacc[2];
#pragma unroll
  for (int db = 0; db < 2; ++db)
#pragma unroll
    for (int r = 0; r < 16; ++r) oacc[db][r] = 0.f;
  float dn = 0.f;

  // reg staging: thread t covers units u = t, t+256 ; (r=u>>3, c=u&7)
  bf16x8 kreg[2], vreg[2];
  auto stage_load = [&](int kt) {
#pragma unroll
    for (int p = 0; p < 2; ++p) {
      int u = p * 256 + t;
      int r = u >> 3, c = u & 7;
      kreg[p] = *reinterpret_cast<const bf16x8*>(&Kh[(size_t)(kt * 64 + r) * 64 + c * 8]);
      vreg[p] = *reinterpret_cast<const bf16x8*>(&Vh[(size_t)r * SEQ + kt * 64 + c * 8]);
    }
  };
  auto stage_write = [&](int buf) {
#pragma unroll
    for (int p = 0; p < 2; ++p) {
      int u = p * 256 + t;
      int r = u >> 3, c = u & 7;
      *reinterpret_cast<bf16x8*>(&lK[buf][(c * 65 + r) * 8]) = kreg[p];
      *reinterpret_cast<bf16x8*>(&lV[buf][(c * 65 + r) * 8]) = vreg[p];
    }
  };

  union PF { u32 w[4]; bf16x8 v; };
  int cur = 0;
  stage_load(0);
  stage_write(0);
  __syncthreads();
  for (int kt = 0; kt < SEQ / 64; ++kt) {
    if (kt + 1 < SEQ / 64) stage_load(kt + 1);  // in flight across compute (T14)

    // ---- QK^T swapped: S^T[k][q] ; lane: q = l31, k = cb*32 + (r&3)+8*(r>>2)+4*hi
    f32x16 s[2];
#pragma unroll
    for (int cb = 0; cb < 2; ++cb)
#pragma unroll
      for (int r = 0; r < 16; ++r) s[cb][r] = 0.f;
    __builtin_amdgcn_s_setprio(1);
#pragma unroll
    for (int cb = 0; cb < 2; ++cb) {
#pragma unroll
      for (int dc = 0; dc < 4; ++dc) {
        bf16x8 kf = *reinterpret_cast<const bf16x8*>(
            &lK[cur][((dc * 2 + hi) * 65 + cb * 32 + l31) * 8]);
        s[cb] = __builtin_amdgcn_mfma_f32_32x32x16_bf16(kf, qf[dc], s[cb], 0, 0, 0);
      }
    }
    __builtin_amdgcn_s_setprio(0);

    // ---- softmax in-register: exp2 (denom unrounded), round-half-up + v_perm pack to bf16
    PF pa[2][2];  // [cb][c(16-k chunk)]
#pragma unroll
    for (int cb = 0; cb < 2; ++cb) {
#pragma unroll
      for (int r = 0; r < 16; ++r) {
        float e = __builtin_amdgcn_exp2f(s[cb][r]);
        s[cb][r] = e;
        dn += e;
      }
#pragma unroll
      for (int c = 0; c < 2; ++c) {
        u32 u0 = f2u(s[cb][8 * c + 0]) + 0x8000u;
        u32 u1 = f2u(s[cb][8 * c + 1]) + 0x8000u;
        u32 u2 = f2u(s[cb][8 * c + 2]) + 0x8000u;
        u32 u3 = f2u(s[cb][8 * c + 3]) + 0x8000u;
        u32 u4 = f2u(s[cb][8 * c + 4]) + 0x8000u;
        u32 u5 = f2u(s[cb][8 * c + 5]) + 0x8000u;
        u32 u6 = f2u(s[cb][8 * c + 6]) + 0x8000u;
        u32 u7 = f2u(s[cb][8 * c + 7]) + 0x8000u;
        u32 a1 = __builtin_amdgcn_perm(u1, u0, 0x07060302);  // bf16(e1)<<16 | bf16(e0)
        u32 a2 = __builtin_amdgcn_perm(u3, u2, 0x07060302);
        u32 b1 = __builtin_amdgcn_perm(u5, u4, 0x07060302);
        u32 b2 = __builtin_amdgcn_perm(u7, u6, 0x07060302);
        asm("v_permlane32_swap_b32 %0, %1" : "+v"(a1), "+v"(b1));
        asm("v_permlane32_swap_b32 %0, %1" : "+v"(a2), "+v"(b2));
        pa[cb][c].w[0] = a1; pa[cb][c].w[1] = a2;
        pa[cb][c].w[2] = b1; pa[cb][c].w[3] = b2;
      }
    }

    // ---- PV: O[q][d] ; A = P (regs), B = V from LDS (col d = l31)
    __builtin_amdgcn_s_setprio(1);
#pragma unroll
    for (int cb = 0; cb < 2; ++cb)
#pragma unroll
      for (int c = 0; c < 2; ++c)
#pragma unroll
        for (int db = 0; db < 2; ++db) {
          bf16x8 vf = *reinterpret_cast<const bf16x8*>(
              &lV[cur][((cb * 4 + c * 2 + hi) * 65 + db * 32 + l31) * 8]);
          oacc[db] = __builtin_amdgcn_mfma_f32_32x32x16_bf16(pa[cb][c].v, vf, oacc[db], 0, 0, 0);
        }
    __builtin_amdgcn_s_setprio(0);

    if (kt + 1 < SEQ / 64) stage_write(cur ^ 1);  // implicit vmcnt wait lands here
    __syncthreads();
    cur ^= 1;
  }

  // ---- epilogue: combine denom halves, normalize, store
  dn += __shfl_xor(dn, 32);
#pragma unroll
  for (int r = 0; r < 16; ++r) {
    int qrel = (r & 3) + 8 * (r >> 2) + 4 * hi;
    float dfull = __shfl(dn, qrel);
    float inv = __builtin_amdgcn_rcpf(dfull);
    int q = q0w + qrel;
#pragma unroll
    for (int db = 0; db < 2; ++db) {
      int d = db * 32 + l31;
      Out[(size_t)(b * SEQ + q) * EMB + h * 64 + d] = f2bf(oacc[db][r] * inv);
    }
  }
}

// ---------------- launch ----------------
extern "C" void kernel_launch(void* const* d_in, const int* in_sizes, int n_in,
                              void* d_out, int out_size, void* d_ws, size_t ws_size,
                              hipStream_t stream) {
  const float* x = (const float*)d_in[0];
  const float* bqkv = (const float*)d_in[2];
  const float* bout = (const float*)d_in[4];
  float* out = (float*)d_out;

  char* ws = (char*)d_ws;
  size_t off = 0;
  auto alloc = [&](size_t bytes) {
    void* p = ws + off;
    off += (bytes + 255) & ~(size_t)255;
    return p;
  };
  u16* xb    = (u16*)alloc((size_t)MTOT * EMB * 2);
  u16* wqkvb = (u16*)alloc((size_t)3 * EMB * EMB * 2);
  u16* woutb = (u16*)alloc((size_t)EMB * EMB * 2);
  u16* Qb    = (u16*)alloc((size_t)64 * SEQ * HD * 2);
  u16* Kb    = (u16*)alloc((size_t)64 * SEQ * HD * 2);
  u16* Vtb   = (u16*)alloc((size_t)64 * HD * SEQ * 2);
  u16* aout  = (u16*)alloc((size_t)MTOT * EMB * 2);
  float* tab2 = (float*)alloc((size_t)SEQ * 32 * 2 * 4);
  (void)ws_size; (void)in_sizes; (void)n_in; (void)out_size;

  cast_kernel<<<2048, 256, 0, stream>>>(x, xb, MTOT * EMB / 4);
  cast_kernel<<<1024, 256, 0, stream>>>((const float*)d_in[1], wqkvb, 3 * EMB * EMB / 4);
  cast_kernel<<<512, 256, 0, stream>>>((const float*)d_in[3], woutb, EMB * EMB / 4);
  rope_table2_kernel<<<(SEQ * 32 + 255) / 256, 256, 0, stream>>>(tab2);

  gemm_qkv_rope<<<64 * 24, 256, 0, stream>>>(xb, wqkvb, bqkv, tab2, Qb, Kb, Vtb);
  attn_kernel<<<64 * 16, 256, 0, stream>>>(Qb, Kb, Vtb, aout);
  gemm_bt_f32<<<64 * 8, 256, 0, stream>>>(aout, woutb, bout, out, EMB, 8);
}